// Round 7
// baseline (46394.177 us; speedup 1.0000x reference)
//
#include <hip/hip_runtime.h>
#include <hip/hip_cooperative_groups.h>
#include <cmath>
#include <cstdint>

namespace cg = cooperative_groups;

#define D_FEAT 6
#define T_SEQ  60
#define HID    256
#define G3     768
#define NROW   2048
#define NSAMP  20480

__device__ __forceinline__ float sigmoidf_(float x) { return 1.0f / (1.0f + expf(-x)); }

// ---------------------------------------------------------------- weight prep
struct PrepArgs {
  const float* src[5];
  float* dst[5];
  int N[5], K[5];
};

__global__ void prep_weights(PrepArgs a) {
  int seg = blockIdx.y;
  const float* S = a.src[seg];
  float* D = a.dst[seg];
  int N = a.N[seg], K = a.K[seg];
  int total = N * K;
  for (int i = blockIdx.x * blockDim.x + threadIdx.x; i < total; i += gridDim.x * blockDim.x) {
    int n = i / K, k = i - n * K;
    D[(size_t)k * N + n] = S[i];   // WT[k][n] = W[n][k]
  }
}

// gate-packed GRU weights: PW0[k][j][4]={r,z,n,0} from Whh0 (k<256);
// PW1[k][j][4] (k<512) from Wih1 (k<256) / Whh1 (k>=256); PX[i][j][4] from Wih0.
__global__ void prep_packed(const float* __restrict__ Whh0, const float* __restrict__ Wih1,
                            const float* __restrict__ Whh1, const float* __restrict__ Wih0,
                            float* __restrict__ PW0, float* __restrict__ PW1,
                            float* __restrict__ PX)
{
  int i = blockIdx.x * 256 + threadIdx.x;     // 512*256 = 131072 threads
  if (i < 65536) {
    int k = i >> 8, j = i & 255;
    float4 v;
    v.x = Whh0[j * 256 + k];
    v.y = Whh0[65536 + j * 256 + k];
    v.z = Whh0[131072 + j * 256 + k];
    v.w = 0.f;
    *(float4*)&PW0[(size_t)i * 4] = v;
  }
  if (i < 131072) {
    int k = i >> 8, j = i & 255;
    float4 v;
    if (k < 256) {
      v.x = Wih1[j * 256 + k];
      v.y = Wih1[65536 + j * 256 + k];
      v.z = Wih1[131072 + j * 256 + k];
    } else {
      int kk = k - 256;
      v.x = Whh1[j * 256 + kk];
      v.y = Whh1[65536 + j * 256 + kk];
      v.z = Whh1[131072 + j * 256 + kk];
    }
    v.w = 0.f;
    *(float4*)&PW1[(size_t)i * 4] = v;
  }
  if (i < 1536) {
    int ii = i >> 8, j = i & 255;
    float4 v;
    v.x = Wih0[j * 6 + ii];
    v.y = Wih0[(256 + j) * 6 + ii];
    v.z = Wih0[(512 + j) * 6 + ii];
    v.w = 0.f;
    *(float4*)&PX[(size_t)i * 4] = v;
  }
}

// ---------------------------------------------------------------- grid-cooperative GRU
// 256 blocks x 1024 threads (16 waves -> 4 waves/SIMD, exactly 1 block/CU).
// Block = (m-tile of 64 stocks) x (j-tile of 32 columns).
// Thread owns (j, 2 stocks, all 3 gates, FULL K) -> per-output fp32 order == R6.
// h ping-pongs in GLOBAL [k][m]=[256][2048]; 2 grid.sync() per step.
__device__ __forceinline__ void kloopX(const float* __restrict__ A,   // + k*2048 (float2 at m)
                                       const float* __restrict__ B,   // + k*1024 (float4 at j)
                                       float (&acc)[3][2])
{
  float2 Aa[8]; float4 Bb[8];
#pragma unroll
  for (int c = 0; c < 8; ++c) {
    Aa[c] = *(const float2*)(A + (size_t)c * 2048);
    Bb[c] = *(const float4*)(B + (size_t)c * 1024);
  }
  for (int kb = 0; kb < 256; kb += 8) {
#pragma unroll
    for (int c = 0; c < 8; ++c) {
      float2 a = Aa[c]; float4 b = Bb[c];
      int kn = (kb + 8 + c) & 255;        // wrap: final prefetch unused
      Aa[c] = *(const float2*)(A + (size_t)kn * 2048);
      Bb[c] = *(const float4*)(B + (size_t)kn * 1024);
      acc[0][0] += a.x * b.x; acc[0][1] += a.y * b.x;
      acc[1][0] += a.x * b.y; acc[1][1] += a.y * b.y;
      acc[2][0] += a.x * b.z; acc[2][1] += a.y * b.z;
    }
  }
}

__global__ __launch_bounds__(1024, 1)
void gru_grid(const float* __restrict__ inp,
              const float* __restrict__ PW0, const float* __restrict__ PW1,
              const float* __restrict__ PX,
              const float* __restrict__ bih0, const float* __restrict__ bhh0,
              const float* __restrict__ bih1, const float* __restrict__ bhh1,
              float* __restrict__ h0T0, float* __restrict__ h0T1,
              float* __restrict__ h1T0, float* __restrict__ h1T1,
              float* __restrict__ hrow)
{
  cg::grid_group grid = cg::this_grid();
  __shared__ float xls[64 * 360];     // 90 KB: x for the block's 64 stocks
  __shared__ float pxs[6144];         // 24 KB: PX copy

  const int tid = threadIdx.x;
  const int jj  = tid & 31;
  const int mg  = tid >> 5;           // 0..31
  const int jb  = blockIdx.x & 7;
  const int mb  = blockIdx.x >> 3;
  const int j   = jb * 32 + jj;
  const int m0  = mb * 64;
  const int m2  = m0 + mg * 2;

  for (int c = tid; c < 64 * 360; c += 1024)
    xls[c] = inp[(size_t)(m0 + c / 360) * 360 + (c % 360)];
  for (int c = tid; c < 6144; c += 1024) pxs[c] = PX[c];

  float b_ih0[3], b_hh0[3], b_ih1[3], b_hh1[3];
#pragma unroll
  for (int u = 0; u < 3; ++u) {
    int o = u * 256 + j;
    b_ih0[u] = bih0[o]; b_hh0[u] = bhh0[o];
    b_ih1[u] = bih1[o]; b_hh1[u] = bhh1[o];
  }

  float h0c[2] = {0.f, 0.f}, h1c[2] = {0.f, 0.f};
  const float* pB0  = PW0 + (size_t)j * 4;                      // + k*1024
  const float* pB1a = PW1 + (size_t)j * 4;                      // k<256
  const float* pB1b = PW1 + (size_t)256 * 1024 + (size_t)j * 4; // k>=256
  __syncthreads();

  for (int t = 0; t < T_SEQ; ++t) {
    const float* h0cur = (t & 1) ? h0T1 : h0T0;
    float*       h0nxt = (t & 1) ? h0T0 : h0T1;
    const float* h1cur = (t & 1) ? h1T1 : h1T0;
    float*       h1nxt = (t & 1) ? h1T0 : h1T1;

    // ---------- layer 0 ----------
    float gh[3][2];
#pragma unroll
    for (int u = 0; u < 3; ++u) { gh[u][0] = 0.f; gh[u][1] = 0.f; }
    kloopX(h0cur + m2, pB0, gh);

    float xw[3][2];
#pragma unroll
    for (int u = 0; u < 3; ++u) { xw[u][0] = b_ih0[u]; xw[u][1] = b_ih0[u]; }
#pragma unroll
    for (int i = 0; i < 6; ++i) {
      float xa0 = xls[(mg * 2) * 360 + i * 60 + t];
      float xa1 = xls[(mg * 2 + 1) * 360 + i * 60 + t];
      float4 b = *(const float4*)&pxs[(i * 256 + j) * 4];
      xw[0][0] += xa0 * b.x; xw[0][1] += xa1 * b.x;
      xw[1][0] += xa0 * b.y; xw[1][1] += xa1 * b.y;
      xw[2][0] += xa0 * b.z; xw[2][1] += xa1 * b.z;
    }
    {
      float hn[2];
#pragma unroll
      for (int s = 0; s < 2; ++s) {
        float rr = sigmoidf_(xw[0][s] + (gh[0][s] + b_hh0[0]));
        float zz = sigmoidf_(xw[1][s] + (gh[1][s] + b_hh0[1]));
        float nn = tanhf(xw[2][s] + rr * (gh[2][s] + b_hh0[2]));
        h0c[s] = (1.f - zz) * nn + zz * h0c[s];
        hn[s] = h0c[s];
      }
      *(float2*)&h0nxt[(size_t)j * 2048 + m2] = *(float2*)hn;
    }
    grid.sync();

    // ---------- layer 1 ----------
    float acc[3][2];
#pragma unroll
    for (int u = 0; u < 3; ++u) { acc[u][0] = 0.f; acc[u][1] = 0.f; }
    kloopX(h0nxt + m2, pB1a, acc);                // x-part: new h0, k 0..255
    float xn[2] = {acc[2][0], acc[2][1]};
    acc[2][0] = 0.f; acc[2][1] = 0.f;
    kloopX(h1cur + m2, pB1b, acc);                // h-part: r/z continue, n fresh
    {
      float hn[2];
#pragma unroll
      for (int s = 0; s < 2; ++s) {
        float rr = sigmoidf_((acc[0][s] + b_ih1[0]) + b_hh1[0]);
        float zz = sigmoidf_((acc[1][s] + b_ih1[1]) + b_hh1[1]);
        float nn = tanhf((xn[s] + b_ih1[2]) + rr * (acc[2][s] + b_hh1[2]));
        h1c[s] = (1.f - zz) * nn + zz * h1c[s];
        hn[s] = h1c[s];
      }
      *(float2*)&h1nxt[(size_t)j * 2048 + m2] = *(float2*)hn;
    }
    grid.sync();
  }

  hrow[(size_t)m2 * 256 + j]       = h1c[0];
  hrow[(size_t)(m2 + 1) * 256 + j] = h1c[1];
}

// ---------------------------------------------------------------- generic GEMM
__global__ __launch_bounds__(256, 2)
void gemm_act(const float* __restrict__ A, const int* __restrict__ rowsrc,
              const float* __restrict__ WT, const float* __restrict__ bias,
              float* __restrict__ C, int M, int N, int K, int act)
{
  __shared__ float4 As4[128 * 32];
  const int tx = threadIdx.x, ty = threadIdx.y;
  const int tid = ty * 32 + tx;
  const int n0 = blockIdx.x * 32, m0 = blockIdx.y * 32;
  const int K4 = K >> 2;

  for (int c = tid; c < K4 * 32; c += 256) {
    int k4 = c % K4, m = c / K4;
    int row = m0 + m;
    if (rowsrc) row = rowsrc[row];
    As4[k4 * 32 + m] = *(const float4*)(A + (size_t)row * K + k4 * 4);
  }
  __syncthreads();

  float acc[4] = {0,0,0,0};
  const int n = n0 + tx;
  const float* pb = WT + n;

  float bc[4], bn_[4];
#pragma unroll
  for (int kk = 0; kk < 4; ++kk) bc[kk] = pb[(size_t)kk * N];
  for (int k4 = 0; k4 < K4; ++k4) {
    int nk4 = (k4 + 1 < K4) ? (k4 + 1) : 0;
    const float* pn = pb + (size_t)nk4 * 4 * N;
#pragma unroll
    for (int kk = 0; kk < 4; ++kk) bn_[kk] = pn[(size_t)kk * N];
    float4 a0 = As4[k4 * 32 + ty * 4 + 0];
    float4 a1 = As4[k4 * 32 + ty * 4 + 1];
    float4 a2 = As4[k4 * 32 + ty * 4 + 2];
    float4 a3 = As4[k4 * 32 + ty * 4 + 3];
#pragma unroll
    for (int kk = 0; kk < 4; ++kk) {
      float b = bc[kk];
      acc[0] += ((const float*)&a0)[kk] * b;
      acc[1] += ((const float*)&a1)[kk] * b;
      acc[2] += ((const float*)&a2)[kk] * b;
      acc[3] += ((const float*)&a3)[kk] * b;
    }
#pragma unroll
    for (int q = 0; q < 4; ++q) bc[q] = bn_[q];
  }
  float bb = bias ? bias[n] : 0.f;
#pragma unroll
  for (int r = 0; r < 4; ++r) {
    float v = acc[r] + bb;
    if (act) v = (v >= 0.f) ? v : 0.01f * v;
    C[(size_t)(m0 + ty * 4 + r) * N + n] = v;
  }
}

// ---------------------------------------------------------------- small stages
__global__ void mbday_part(const float* __restrict__ mbf, float* __restrict__ part) {
  int d = blockIdx.x, sl = blockIdx.y, c = threadIdx.x;
  float s = 0.f;
  int base = d * 512 + sl * 64;
  for (int st = 0; st < 64; ++st) s += mbf[(size_t)(base + st) * 256 + c];
  part[(size_t)(d * 8 + sl) * 256 + c] = s;
}

__global__ void mbday_fin(const float* __restrict__ part, float* __restrict__ mbday) {
  int d = blockIdx.x, c = threadIdx.x;
  float s = 0.f;
#pragma unroll
  for (int p = 0; p < 8; ++p) s += part[(size_t)(d * 8 + p) * 256 + c];
  mbday[d * 256 + c] = s * (1.0f / 512.0f);
}

__global__ void daytopk_kernel(const float* __restrict__ mbday, const float* __restrict__ thd,
                               int* __restrict__ dayidx) {
  __shared__ float mbs[256];
  __shared__ float sim[256];
  __shared__ float red[256];
  __shared__ int   redi[256];
  const int d = blockIdx.x, t = threadIdx.x;
  mbs[t] = mbday[d * 256 + t];
  __syncthreads();
  red[t] = mbs[t] * mbs[t];
  __syncthreads();
  for (int o = 128; o; o >>= 1) { if (t < o) red[t] += red[t + o]; __syncthreads(); }
  float xn = sqrtf(red[0]);
  float v = -INFINITY;
  if (t < 240) {
    float dot = 0.f, yn2 = 0.f;
    for (int k = 0; k < 256; ++k) {
      float y = thd[t * 256 + k];
      dot += mbs[k] * y;
      yn2 += y * y;
    }
    float den = xn * sqrtf(yn2);
    v = (den > 0.f) ? dot / den : 0.f;
  }
  sim[t] = v;
  __syncthreads();
  for (int it = 0; it < 10; ++it) {
    red[t] = sim[t]; redi[t] = t;
    __syncthreads();
    for (int o = 128; o; o >>= 1) {
      if (t < o) {
        if (red[t + o] > red[t] || (red[t + o] == red[t] && redi[t + o] < redi[t])) {
          red[t] = red[t + o]; redi[t] = redi[t + o];
        }
      }
      __syncthreads();
    }
    if (t == 0) { int bi = redi[0]; dayidx[d * 10 + it] = bi; sim[bi] = -INFINITY; }
    __syncthreads();
  }
}

__global__ void rowsrc_kernel(const int* __restrict__ dayidx, int* __restrict__ rowsrc) {
  int r = blockIdx.x * 256 + threadIdx.x;
  if (r < NSAMP) rowsrc[r] = dayidx[r >> 9] * 512 + (r & 511);
}

__global__ void rownorm_kernel(const float* __restrict__ X, float* __restrict__ out, int rows) {
  int w = threadIdx.x >> 6;
  int lane = threadIdx.x & 63;
  int row = blockIdx.x * 4 + w;
  if (row >= rows) return;
  float4 x = *(const float4*)(X + (size_t)row * 256 + lane * 4);
  float s = x.x * x.x + x.y * x.y + x.z * x.z + x.w * x.w;
#pragma unroll
  for (int o = 32; o; o >>= 1) s += __shfl_down(s, o, 64);
  if (lane == 0) out[row] = sqrtf(s);
}

__global__ void qnorm_kernel(float* __restrict__ q, const float* __restrict__ qn) {
  int i = blockIdx.x * 256 + threadIdx.x;
  int row = i >> 8;
  float n = qn[row];
  q[i] = (n > 0.f) ? q[i] / n : 0.f;
}

__global__ void khT_kernel(const float* __restrict__ kh, const float* __restrict__ khn,
                           float* __restrict__ khT) {
  __shared__ float tile[32][33];
  int jb = blockIdx.x * 32;
  int kb = blockIdx.y * 32;
  int tx = threadIdx.x & 31, tyy = threadIdx.x >> 5;
  for (int rr = tyy; rr < 32; rr += 8) {
    float n = khn[jb + rr];
    float v = kh[(size_t)(jb + rr) * 256 + kb + tx];
    tile[rr][tx] = (n > 0.f) ? v / n : 0.f;
  }
  __syncthreads();
  for (int rr = tyy; rr < 32; rr += 8) {
    khT[(size_t)(kb + rr) * NSAMP + jb + tx] = tile[tx][rr];
  }
}

// ---------------------------------------------------------------- cs GEMM + top-10 (split, XCD-swizzled)
__global__ __launch_bounds__(256, 4)
void csmax_kernel(const float* __restrict__ qh, const float* __restrict__ khT,
                  float* __restrict__ topvp, int* __restrict__ topip)
{
  __shared__ float4 qs[256][2];
  __shared__ float csch[8 * 512];
  const int tid = threadIdx.x;
  const int split = blockIdx.x & 7;
  const int m0 = (blockIdx.x >> 3) * 8;
  {
    int k = tid;
    float4 v0, v1;
    v0.x = qh[(size_t)(m0 + 0) * 256 + k]; v0.y = qh[(size_t)(m0 + 1) * 256 + k];
    v0.z = qh[(size_t)(m0 + 2) * 256 + k]; v0.w = qh[(size_t)(m0 + 3) * 256 + k];
    v1.x = qh[(size_t)(m0 + 4) * 256 + k]; v1.y = qh[(size_t)(m0 + 5) * 256 + k];
    v1.z = qh[(size_t)(m0 + 6) * 256 + k]; v1.w = qh[(size_t)(m0 + 7) * 256 + k];
    qs[k][0] = v0; qs[k][1] = v1;
  }
  __syncthreads();
  const int lane = tid & 63;
  const int wv = tid >> 6;

  float tv0[10], tv1[10];
  int   tj0[10], tj1[10];
  int   tn0 = 0, tn1 = 0;
  float tmv0 = -INFINITY, tmv1 = -INFINITY;
  int   tmi0 = 0, tmi1 = 0;

  auto process_row = [&](int r, float (&tv)[10], int (&tj)[10], int& tn,
                         float& tmv, int& tmi, int jb) {
    float4 c0 = *(const float4*)&csch[r * 512 + lane * 8];
    float4 c1 = *(const float4*)&csch[r * 512 + lane * 8 + 4];
    float cv[8] = {c0.x, c0.y, c0.z, c0.w, c1.x, c1.y, c1.z, c1.w};
    const int cj0 = jb + lane * 8;
    while (true) {
      float bv = -INFINITY; int bj = 0x7fffffff;
#pragma unroll
      for (int u = 0; u < 8; ++u) {
        if (cv[u] > bv) { bv = cv[u]; bj = cj0 + u; }
      }
#pragma unroll
      for (int o = 32; o; o >>= 1) {
        float ov = __shfl_down(bv, o, 64);
        int   oj = __shfl_down(bj, o, 64);
        if (ov > bv || (ov == bv && oj < bj)) { bv = ov; bj = oj; }
      }
      bv = __shfl(bv, 0, 64); bj = __shfl(bj, 0, 64);
      bool take;
      if (tn < 10) take = true;
      else take = (bv > tmv) || (bv == tmv && bj < tmi);
      if (!take) break;
      if (tn < 10) {
#pragma unroll
        for (int s = 0; s < 10; ++s) if (s == tn) { tv[s] = bv; tj[s] = bj; }
        tn++;
        if (tn == 10) {
          float mv = tv[0]; int mi = tj[0];
#pragma unroll
          for (int s = 1; s < 10; ++s) {
            bool w = (tv[s] < mv) || (tv[s] == mv && tj[s] > mi);
            if (w) { mv = tv[s]; mi = tj[s]; }
          }
          tmv = mv; tmi = mi;
        }
      } else {
        int ms = 0; float mv = tv[0]; int mi = tj[0];
#pragma unroll
        for (int s = 1; s < 10; ++s) {
          bool w = (tv[s] < mv) || (tv[s] == mv && tj[s] > mi);
          if (w) { ms = s; mv = tv[s]; mi = tj[s]; }
        }
#pragma unroll
        for (int s = 0; s < 10; ++s) if (s == ms) { tv[s] = bv; tj[s] = bj; }
        mv = tv[0]; mi = tj[0];
#pragma unroll
        for (int s = 1; s < 10; ++s) {
          bool w = (tv[s] < mv) || (tv[s] == mv && tj[s] > mi);
          if (w) { mv = tv[s]; mi = tj[s]; }
        }
        tmv = mv; tmi = mi;
      }
#pragma unroll
      for (int u = 0; u < 8; ++u) if (cj0 + u == bj) cv[u] = -INFINITY;
    }
  };

  for (int ci = 0; ci < 5; ++ci) {
    const int ch = split * 5 + ci;
    const int jb = ch * 512;
    float acc[8][2];
#pragma unroll
    for (int r = 0; r < 8; ++r) { acc[r][0] = 0.f; acc[r][1] = 0.f; }
    const float* kp = khT + jb + tid;

    float b0c[4], b1c[4], b0n[4], b1n[4];
#pragma unroll
    for (int kk = 0; kk < 4; ++kk) {
      b0c[kk] = kp[(size_t)kk * NSAMP];
      b1c[kk] = kp[(size_t)kk * NSAMP + 256];
    }
    for (int k4 = 0; k4 < 64; ++k4) {
      int nk4 = (k4 + 1) & 63;
      const float* pn = kp + (size_t)nk4 * 4 * NSAMP;
#pragma unroll
      for (int kk = 0; kk < 4; ++kk) {
        b0n[kk] = pn[(size_t)kk * NSAMP];
        b1n[kk] = pn[(size_t)kk * NSAMP + 256];
      }
#pragma unroll
      for (int kk = 0; kk < 4; ++kk) {
        float4 qa = qs[k4 * 4 + kk][0];
        float4 qb = qs[k4 * 4 + kk][1];
        float b0 = b0c[kk], b1 = b1c[kk];
        acc[0][0] += qa.x * b0; acc[1][0] += qa.y * b0; acc[2][0] += qa.z * b0; acc[3][0] += qa.w * b0;
        acc[4][0] += qb.x * b0; acc[5][0] += qb.y * b0; acc[6][0] += qb.z * b0; acc[7][0] += qb.w * b0;
        acc[0][1] += qa.x * b1; acc[1][1] += qa.y * b1; acc[2][1] += qa.z * b1; acc[3][1] += qa.w * b1;
        acc[4][1] += qb.x * b1; acc[5][1] += qb.y * b1; acc[6][1] += qb.z * b1; acc[7][1] += qb.w * b1;
      }
#pragma unroll
      for (int q = 0; q < 4; ++q) { b0c[q] = b0n[q]; b1c[q] = b1n[q]; }
    }
    __syncthreads();
#pragma unroll
    for (int r = 0; r < 8; ++r) {
      csch[r * 512 + tid] = acc[r][0];
      csch[r * 512 + 256 + tid] = acc[r][1];
    }
    __syncthreads();
    process_row(wv,     tv0, tj0, tn0, tmv0, tmi0, jb);
    process_row(wv + 4, tv1, tj1, tn1, tmv1, tmi1, jb);
  }
  __syncthreads();

  if (lane == 0) {
    int row0 = m0 + wv;
#pragma unroll
    for (int s = 0; s < 10; ++s) {
      topvp[(size_t)row0 * 80 + split * 10 + s] = tv0[s];
      topip[(size_t)row0 * 80 + split * 10 + s] = tj0[s];
    }
    int row1 = m0 + wv + 4;
#pragma unroll
    for (int s = 0; s < 10; ++s) {
      topvp[(size_t)row1 * 80 + split * 10 + s] = tv1[s];
      topip[(size_t)row1 * 80 + split * 10 + s] = tj1[s];
    }
  }
}

// merge 8 splits x 10 candidates -> global top-10 per row (value desc, idx asc)
__global__ void merge_topk(const float* __restrict__ topvp, const int* __restrict__ topip,
                           float* __restrict__ topv, int* __restrict__ topi)
{
  const int wv = threadIdx.x >> 6;
  const int lane = threadIdx.x & 63;
  const int row = blockIdx.x * 4 + wv;
  float v0 = topvp[(size_t)row * 80 + lane];
  int   i0 = topip[(size_t)row * 80 + lane];
  float v1 = (lane < 16) ? topvp[(size_t)row * 80 + 64 + lane] : -INFINITY;
  int   i1 = (lane < 16) ? topip[(size_t)row * 80 + 64 + lane] : 0x7fffffff;
  for (int s = 0; s < 10; ++s) {
    float bv = v0; int bj = i0;
    if (v1 > bv || (v1 == bv && i1 < bj)) { bv = v1; bj = i1; }
#pragma unroll
    for (int o = 1; o < 64; o <<= 1) {
      float ov = __shfl_xor(bv, o, 64);
      int   oj = __shfl_xor(bj, o, 64);
      if (ov > bv || (ov == bv && oj < bj)) { bv = ov; bj = oj; }
    }
    if (lane == 0) { topv[row * 10 + s] = bv; topi[row * 10 + s] = bj; }
    if (i0 == bj) { v0 = -INFINITY; i0 = 0x7fffffff; }
    if (i1 == bj) { v1 = -INFINITY; i1 = 0x7fffffff; }
  }
}

// ---------------------------------------------------------------- final: agg + fc
__global__ void final_kernel(const float* __restrict__ mb, const float* __restrict__ kh,
                             const float* __restrict__ topv, const int* __restrict__ topi,
                             const float* __restrict__ fcW, const float* __restrict__ fcb,
                             float* __restrict__ y)
{
  __shared__ float red[256];
  int n = blockIdx.x, c = threadIdx.x;
  float agg = 0.f;
#pragma unroll
  for (int k = 0; k < 10; ++k) {
    float w = topv[n * 10 + k] / 10.0f;
    int idx = topi[n * 10 + k];
    agg += w * kh[(size_t)idx * 256 + c];
  }
  float val = fcW[c] * mb[(size_t)n * 256 + c] + fcW[256 + c] * agg;
  red[c] = val;
  __syncthreads();
  for (int o = 128; o; o >>= 1) { if (c < o) red[c] += red[c + o]; __syncthreads(); }
  if (c == 0) y[n] = red[0] + fcb[0];
}

// ---------------------------------------------------------------- launch
extern "C" void kernel_launch(void* const* d_in, const int* in_sizes, int n_in,
                              void* d_out, int out_size, void* d_ws, size_t ws_size,
                              hipStream_t stream)
{
  const float* inp    = (const float*)d_in[0];
  const float* trainh = (const float*)d_in[1];
  const float* thd    = (const float*)d_in[2];
  const float* Wih0   = (const float*)d_in[3];
  const float* Whh0   = (const float*)d_in[4];
  const float* bih0   = (const float*)d_in[5];
  const float* bhh0   = (const float*)d_in[6];
  const float* Wih1   = (const float*)d_in[7];
  const float* Whh1   = (const float*)d_in[8];
  const float* bih1   = (const float*)d_in[9];
  const float* bhh1   = (const float*)d_in[10];
  const float* lin0W  = (const float*)d_in[11];
  const float* lin0b  = (const float*)d_in[12];
  const float* lin1W  = (const float*)d_in[13];
  const float* lin1b  = (const float*)d_in[14];
  const float* lin2W  = (const float*)d_in[15];
  const float* lin2b  = (const float*)d_in[16];
  const float* p1W    = (const float*)d_in[17];
  const float* p2W    = (const float*)d_in[18];
  const float* fcW    = (const float*)d_in[19];
  const float* fcb    = (const float*)d_in[20];

  float* ws = (float*)d_ws;
  float* PW0    = ws + 0;          // 256x256x4 = 262144
  float* PW1    = ws + 262144;     // 512x256x4 = 524288
  float* PX     = ws + 786432;     // 6x256x4   = 6144
  float* WT_l0  = ws + 792576;     // 256x512
  float* WT_l1  = ws + 923648;     // 512x512
  float* WT_l2  = ws + 1185792;    // 512x256
  float* WT_p1  = ws + 1316864;    // 256x256
  float* WT_p2  = ws + 1382400;    // 256x256
  float* mb1    = ws + 1447936;    // 2048x512 (topvp/topip reuse)
  float* mb2    = ws + 2496512;    // 2048x512 (mbpart reuse)
  float* mbf    = ws + 3545088;    // 2048x256
  float* mbday  = ws + 4069376;    // 4x256
  float* qbuf   = ws + 4070400;    // 2048x256
  float* kh     = ws + 4594688;    // 20480x256  (h0/h1 ping-pong during GRU)
  float* khT    = ws + 9837568;    // 256x20480  (hrow during GRU/MLP phase)
  float* khn    = ws + 15080448;   // 20480
  float* qn     = ws + 15100928;   // 2048
  float* topv   = ws + 15102976;   // 2048x10
  int*   dayidx = (int*)(ws + 15123456);
  int*   rowsrc = (int*)(ws + 15123520);
  int*   topi   = (int*)(ws + 15144000);
  // overlays
  float* h0T0   = kh;                      // 256x2048 each
  float* h0T1   = kh + 524288;
  float* h1T0   = kh + 1048576;
  float* h1T1   = kh + 1572864;
  float* hrow   = khT;                     // 2048x256, dead before khT written
  float* topvp  = mb1;                     // 2048x80
  int*   topip  = (int*)(mb1 + 163840);
  float* mbpart = mb2;                     // 4x8x256

  PrepArgs pa;
  pa.src[0] = lin0W; pa.dst[0] = WT_l0; pa.N[0] = 512; pa.K[0] = 256;
  pa.src[1] = lin1W; pa.dst[1] = WT_l1; pa.N[1] = 512; pa.K[1] = 512;
  pa.src[2] = lin2W; pa.dst[2] = WT_l2; pa.N[2] = 256; pa.K[2] = 512;
  pa.src[3] = p1W;   pa.dst[3] = WT_p1; pa.N[3] = 256; pa.K[3] = 256;
  pa.src[4] = p2W;   pa.dst[4] = WT_p2; pa.N[4] = 256; pa.K[4] = 256;
  prep_weights<<<dim3(64, 5), dim3(256), 0, stream>>>(pa);
  prep_packed<<<512, 256, 0, stream>>>(Whh0, Wih1, Whh1, Wih0, PW0, PW1, PX);

  hipMemsetAsync(h0T0, 0, (size_t)524288 * 4, stream);
  hipMemsetAsync(h1T0, 0, (size_t)524288 * 4, stream);

  {
    const float* a_inp = inp;
    const float* a_pw0 = PW0; const float* a_pw1 = PW1; const float* a_px = PX;
    const float* a_b0i = bih0; const float* a_b0h = bhh0;
    const float* a_b1i = bih1; const float* a_b1h = bhh1;
    float* a_h00 = h0T0; float* a_h01 = h0T1;
    float* a_h10 = h1T0; float* a_h11 = h1T1;
    float* a_hr = hrow;
    void* kargs[] = { (void*)&a_inp, (void*)&a_pw0, (void*)&a_pw1, (void*)&a_px,
                      (void*)&a_b0i, (void*)&a_b0h, (void*)&a_b1i, (void*)&a_b1h,
                      (void*)&a_h00, (void*)&a_h01, (void*)&a_h10, (void*)&a_h11,
                      (void*)&a_hr };
    hipLaunchCooperativeKernel((const void*)gru_grid, dim3(256), dim3(1024),
                               kargs, 0, stream);
  }

  gemm_act<<<dim3(16, 64), dim3(32, 8), 0, stream>>>(hrow, nullptr, WT_l0, lin0b, mb1, 2048, 512, 256, 1);
  gemm_act<<<dim3(16, 64), dim3(32, 8), 0, stream>>>(mb1, nullptr, WT_l1, lin1b, mb2, 2048, 512, 512, 1);
  gemm_act<<<dim3(8, 64),  dim3(32, 8), 0, stream>>>(mb2, nullptr, WT_l2, lin2b, mbf, 2048, 256, 512, 1);

  mbday_part<<<dim3(4, 8), 256, 0, stream>>>(mbf, mbpart);
  mbday_fin<<<4, 256, 0, stream>>>(mbpart, mbday);
  daytopk_kernel<<<4, 256, 0, stream>>>(mbday, thd, dayidx);
  rowsrc_kernel<<<80, 256, 0, stream>>>(dayidx, rowsrc);

  gemm_act<<<dim3(8, 640), dim3(32, 8), 0, stream>>>(trainh, rowsrc, WT_p2, nullptr, kh, 20480, 256, 256, 0);
  gemm_act<<<dim3(8, 64),  dim3(32, 8), 0, stream>>>(mbf, nullptr, WT_p1, nullptr, qbuf, 2048, 256, 256, 0);

  rownorm_kernel<<<5120, 256, 0, stream>>>(kh, khn, 20480);
  rownorm_kernel<<<512, 256, 0, stream>>>(qbuf, qn, 2048);
  qnorm_kernel<<<2048, 256, 0, stream>>>(qbuf, qn);
  khT_kernel<<<dim3(640, 8), 256, 0, stream>>>(kh, khn, khT);

  csmax_kernel<<<2048, 256, 0, stream>>>(qbuf, khT, topvp, topip);
  merge_topk<<<512, 256, 0, stream>>>(topvp, topip, topv, topi);
  final_kernel<<<2048, 256, 0, stream>>>(mbf, kh, topv, topi, fcW, fcb, (float*)d_out);

  (void)in_sizes; (void)n_in; (void)out_size; (void)ws_size;
}

// Round 8
// 4652.059 us; speedup vs baseline: 9.9728x; 9.9728x over previous
//
#include <hip/hip_runtime.h>
#include <cmath>
#include <cstdint>

#define D_FEAT 6
#define T_SEQ  60
#define HID    256
#define G3     768
#define NROW   2048
#define NSAMP  20480

__device__ __forceinline__ float sigmoidf_(float x) { return 1.0f / (1.0f + expf(-x)); }

// ---------------------------------------------------------------- weight prep
struct PrepArgs {
  const float* src[9];
  float* dst[9];
  int N[9], K[9], ro[9];
};

__global__ void prep_weights(PrepArgs a) {
  int seg = blockIdx.y;
  const float* S = a.src[seg];
  float* D = a.dst[seg];
  int N = a.N[seg], K = a.K[seg], ro = a.ro[seg];
  int total = N * K;
  for (int i = blockIdx.x * blockDim.x + threadIdx.x; i < total; i += gridDim.x * blockDim.x) {
    int n = i / K, k = i - n * K;
    D[(size_t)(k + ro) * N + n] = S[i];   // WT[k][n] = W[n][k]
  }
}

// ---------------------------------------------------------------- persistent pipelined GRU v4
// Grid 256 x 1024 threads (16 waves -> 4 waves/SIMD). Block owns 8 stocks.
// Thread (col = tid&255, khalf = (tid>>8)&1, mhalf = tid>>9) computes the
// khalf-K partial of outputs o = {col, 256+col, 512+col} for rows mhalf*4..+3.
// PIPELINED: phase p computes layer0(t=p) AND layer1(t=p-1) (both depend only
// on h0(p-1), h1(p-2)) -> 61 phases x 2 barriers (vs R6's 240 barriers).
// Partial-sum reduction order is bit-identical to R6 (absmax 0.0 preserved).
__device__ __forceinline__ void kloop128q(const float* __restrict__ A,  // LDS + k*8 (at row offset)
                                          const float* __restrict__ B,  // global + k*768 (at col)
                                          float (&acc)[3][4])
{
  float4 Aa[4];
  float  Bb[2][12];
#pragma unroll
  for (int c = 0; c < 4; ++c) Aa[c] = *(const float4*)(A + c * 8);
#pragma unroll
  for (int c = 0; c < 4; ++c)
#pragma unroll
    for (int u = 0; u < 3; ++u)
      Bb[0][c * 3 + u] = B[(size_t)c * G3 + u * 256];

  for (int kb = 0; kb < 128; kb += 8) {
    {
      const float* p = B + (size_t)(kb + 4) * G3;
#pragma unroll
      for (int c = 0; c < 4; ++c)
#pragma unroll
        for (int u = 0; u < 3; ++u)
          Bb[1][c * 3 + u] = p[(size_t)c * G3 + u * 256];
    }
#pragma unroll
    for (int c = 0; c < 4; ++c) {
      float4 a = Aa[c];
      int kn = kb + 4 + c;              // <=127
      Aa[c] = *(const float4*)(A + kn * 8);
#pragma unroll
      for (int u = 0; u < 3; ++u) {
        float b = Bb[0][c * 3 + u];
        acc[u][0] += a.x * b; acc[u][1] += a.y * b;
        acc[u][2] += a.z * b; acc[u][3] += a.w * b;
      }
    }
    {
      int kw = (kb + 8) & 127;          // wrap: last prefetch unused
      const float* p = B + (size_t)kw * G3;
#pragma unroll
      for (int c = 0; c < 4; ++c)
#pragma unroll
        for (int u = 0; u < 3; ++u)
          Bb[0][c * 3 + u] = p[(size_t)c * G3 + u * 256];
    }
#pragma unroll
    for (int c = 0; c < 4; ++c) {
      float4 a = Aa[c];
      int kn = (kb + 8 + c) & 127;
      Aa[c] = *(const float4*)(A + kn * 8);
#pragma unroll
      for (int u = 0; u < 3; ++u) {
        float b = Bb[1][c * 3 + u];
        acc[u][0] += a.x * b; acc[u][1] += a.y * b;
        acc[u][2] += a.z * b; acc[u][3] += a.w * b;
      }
    }
  }
}

__global__ __launch_bounds__(1024, 1)
void gru_pipe(const float* __restrict__ inp, const float* __restrict__ WThh0,
              const float* __restrict__ WTcat, const float* __restrict__ WTih0,
              const float* __restrict__ bih0, const float* __restrict__ bhh0,
              const float* __restrict__ bih1, const float* __restrict__ bhh1,
              float* __restrict__ hrow)
{
  __shared__ float h0A[2048], h0B[2048];   // [k*8+row] ping-pong
  __shared__ float h1A[2048], h1B[2048];
  __shared__ float xls[2880];              // [(i*60+t)*8 + row]
  __shared__ float exch[512 * 29];         // partial exchange, pitch 29 (2-way alias = free)

  const int tid = threadIdx.x;
  const int col = tid & 255;
  const int sub = tid >> 8;
  const int khalf = sub & 1;
  const int mhalf = sub >> 1;
  const int m0 = blockIdx.x * 8;
  const int aoff = khalf * 1024 + mhalf * 4;   // into h tiles [k*8+row]

  for (int c = tid; c < 2880; c += 1024) {
    int row = c / 360, it = c - row * 360;
    xls[it * 8 + row] = inp[(size_t)(m0 + row) * 360 + it];
  }
  // h0A = h0(-1) = 0 (phase 0 cur); h1B = h1(-1) = 0 (phase 1 cur)
  for (int c = tid; c < 2048; c += 1024) { h0A[c] = 0.f; h1B[c] = 0.f; }

  float h0c[4] = {0,0,0,0}, h1c[4] = {0,0,0,0};   // live on khalf 0 only

  float b_ih0[3], b_hh0[3], b_ih1[3], b_hh1[3];
#pragma unroll
  for (int u = 0; u < 3; ++u) {
    int o = u * 256 + col;
    b_ih0[u] = bih0[o]; b_hh0[u] = bhh0[o];
    b_ih1[u] = bih1[o]; b_hh1[u] = bhh1[o];
  }
  __syncthreads();

  const float* Bhh0 = WThh0 + (size_t)(khalf * 128) * G3 + col;
  const float* Bc0  = WTcat + (size_t)(khalf * 128) * G3 + col;
  const float* Bc1  = WTcat + (size_t)(256 + khalf * 128) * G3 + col;
  float* exc = exch + (col * 2 + mhalf) * 29;

  for (int p = 0; p <= 60; ++p) {
    const float* h0cur = (p & 1) ? h0B : h0A;
    float*       h0nxt = (p & 1) ? h0A : h0B;
    const float* h1cur = (p & 1) ? h1B : h1A;
    float*       h1nxt = (p & 1) ? h1A : h1B;

    float gh[3][4];
    float l1[3][4];
    float xn4[4];
    if (p < 60) {
#pragma unroll
      for (int u = 0; u < 3; ++u)
#pragma unroll
        for (int r = 0; r < 4; ++r) gh[u][r] = 0.f;
      kloop128q(h0cur + aoff, Bhh0, gh);       // layer0(t=p) h-part, khalf range
    }
    if (p > 0) {
#pragma unroll
      for (int u = 0; u < 3; ++u)
#pragma unroll
        for (int r = 0; r < 4; ++r) l1[u][r] = 0.f;
      kloop128q(h0cur + aoff, Bc0, l1);        // layer1(t=p-1) x-part over h0(p-1)
#pragma unroll
      for (int r = 0; r < 4; ++r) { xn4[r] = l1[2][r]; l1[2][r] = 0.f; }
      kloop128q(h1cur + aoff, Bc1, l1);        // layer1 h-part: r/z continue, n fresh
    }

    float xw[3][4];
    if (khalf == 1) {
      if (p < 60) {
#pragma unroll
        for (int u = 0; u < 3; ++u)
#pragma unroll
          for (int r = 0; r < 4; ++r) exc[u * 4 + r] = gh[u][r];
      }
      if (p > 0) {
#pragma unroll
        for (int r = 0; r < 4; ++r) {
          exc[12 + r] = l1[0][r];
          exc[16 + r] = l1[1][r];
          exc[20 + r] = xn4[r];
          exc[24 + r] = l1[2][r];
        }
      }
    } else if (p < 60) {
      // overlap with khalf1's partial writes: layer0 x-part (K=6)
#pragma unroll
      for (int u = 0; u < 3; ++u)
#pragma unroll
        for (int r = 0; r < 4; ++r) xw[u][r] = b_ih0[u];
#pragma unroll
      for (int i = 0; i < 6; ++i) {
        float x0 = xls[(i * 60 + p) * 8 + mhalf * 4 + 0];
        float x1 = xls[(i * 60 + p) * 8 + mhalf * 4 + 1];
        float x2 = xls[(i * 60 + p) * 8 + mhalf * 4 + 2];
        float x3 = xls[(i * 60 + p) * 8 + mhalf * 4 + 3];
#pragma unroll
        for (int u = 0; u < 3; ++u) {
          float b = WTih0[i * G3 + u * 256 + col];
          xw[u][0] += x0 * b; xw[u][1] += x1 * b;
          xw[u][2] += x2 * b; xw[u][3] += x3 * b;
        }
      }
    }
    __syncthreads();

    if (khalf == 0) {
      if (p < 60) {
        float hn[4];
#pragma unroll
        for (int r = 0; r < 4; ++r) {
          float g0 = gh[0][r] + exc[r];
          float g1 = gh[1][r] + exc[4 + r];
          float g2 = gh[2][r] + exc[8 + r];
          float rr = sigmoidf_(xw[0][r] + (g0 + b_hh0[0]));
          float zz = sigmoidf_(xw[1][r] + (g1 + b_hh0[1]));
          float nn = tanhf(xw[2][r] + rr * (g2 + b_hh0[2]));
          h0c[r] = (1.f - zz) * nn + zz * h0c[r];
          hn[r] = h0c[r];
        }
        *(float4*)&h0nxt[col * 8 + mhalf * 4] = *(float4*)hn;
      }
      if (p > 0) {
        float hn[4];
#pragma unroll
        for (int r = 0; r < 4; ++r) {
          float ra = l1[0][r] + exc[12 + r];
          float za = l1[1][r] + exc[16 + r];
          float xa = xn4[r] + exc[20 + r];
          float ha = l1[2][r] + exc[24 + r];
          float rr = sigmoidf_((ra + b_ih1[0]) + b_hh1[0]);
          float zz = sigmoidf_((za + b_ih1[1]) + b_hh1[1]);
          float nn = tanhf((xa + b_ih1[2]) + rr * (ha + b_hh1[2]));
          h1c[r] = (1.f - zz) * nn + zz * h1c[r];
          hn[r] = h1c[r];
        }
        *(float4*)&h1nxt[col * 8 + mhalf * 4] = *(float4*)hn;
      }
    }
    __syncthreads();
  }

  if (khalf == 0) {
#pragma unroll
    for (int r = 0; r < 4; ++r)
      hrow[(size_t)(m0 + mhalf * 4 + r) * 256 + col] = h1c[r];
  }
}

// ---------------------------------------------------------------- generic GEMM
__global__ __launch_bounds__(256, 2)
void gemm_act(const float* __restrict__ A, const int* __restrict__ rowsrc,
              const float* __restrict__ WT, const float* __restrict__ bias,
              float* __restrict__ C, int M, int N, int K, int act)
{
  __shared__ float4 As4[128 * 32];
  const int tx = threadIdx.x, ty = threadIdx.y;
  const int tid = ty * 32 + tx;
  const int n0 = blockIdx.x * 32, m0 = blockIdx.y * 32;
  const int K4 = K >> 2;

  for (int c = tid; c < K4 * 32; c += 256) {
    int k4 = c % K4, m = c / K4;
    int row = m0 + m;
    if (rowsrc) row = rowsrc[row];
    As4[k4 * 32 + m] = *(const float4*)(A + (size_t)row * K + k4 * 4);
  }
  __syncthreads();

  float acc[4] = {0,0,0,0};
  const int n = n0 + tx;
  const float* pb = WT + n;

  float bc[4], bn_[4];
#pragma unroll
  for (int kk = 0; kk < 4; ++kk) bc[kk] = pb[(size_t)kk * N];
  for (int k4 = 0; k4 < K4; ++k4) {
    int nk4 = (k4 + 1 < K4) ? (k4 + 1) : 0;
    const float* pn = pb + (size_t)nk4 * 4 * N;
#pragma unroll
    for (int kk = 0; kk < 4; ++kk) bn_[kk] = pn[(size_t)kk * N];
    float4 a0 = As4[k4 * 32 + ty * 4 + 0];
    float4 a1 = As4[k4 * 32 + ty * 4 + 1];
    float4 a2 = As4[k4 * 32 + ty * 4 + 2];
    float4 a3 = As4[k4 * 32 + ty * 4 + 3];
#pragma unroll
    for (int kk = 0; kk < 4; ++kk) {
      float b = bc[kk];
      acc[0] += ((const float*)&a0)[kk] * b;
      acc[1] += ((const float*)&a1)[kk] * b;
      acc[2] += ((const float*)&a2)[kk] * b;
      acc[3] += ((const float*)&a3)[kk] * b;
    }
#pragma unroll
    for (int q = 0; q < 4; ++q) bc[q] = bn_[q];
  }
  float bb = bias ? bias[n] : 0.f;
#pragma unroll
  for (int r = 0; r < 4; ++r) {
    float v = acc[r] + bb;
    if (act) v = (v >= 0.f) ? v : 0.01f * v;
    C[(size_t)(m0 + ty * 4 + r) * N + n] = v;
  }
}

// ---------------------------------------------------------------- small stages
__global__ void mbday_part(const float* __restrict__ mbf, float* __restrict__ part) {
  int d = blockIdx.x, sl = blockIdx.y, c = threadIdx.x;
  float s = 0.f;
  int base = d * 512 + sl * 64;
  for (int st = 0; st < 64; ++st) s += mbf[(size_t)(base + st) * 256 + c];
  part[(size_t)(d * 8 + sl) * 256 + c] = s;
}

__global__ void mbday_fin(const float* __restrict__ part, float* __restrict__ mbday) {
  int d = blockIdx.x, c = threadIdx.x;
  float s = 0.f;
#pragma unroll
  for (int p = 0; p < 8; ++p) s += part[(size_t)(d * 8 + p) * 256 + c];
  mbday[d * 256 + c] = s * (1.0f / 512.0f);
}

__global__ void daytopk_kernel(const float* __restrict__ mbday, const float* __restrict__ thd,
                               int* __restrict__ dayidx) {
  __shared__ float mbs[256];
  __shared__ float sim[256];
  __shared__ float red[256];
  __shared__ int   redi[256];
  const int d = blockIdx.x, t = threadIdx.x;
  mbs[t] = mbday[d * 256 + t];
  __syncthreads();
  red[t] = mbs[t] * mbs[t];
  __syncthreads();
  for (int o = 128; o; o >>= 1) { if (t < o) red[t] += red[t + o]; __syncthreads(); }
  float xn = sqrtf(red[0]);
  float v = -INFINITY;
  if (t < 240) {
    float dot = 0.f, yn2 = 0.f;
    for (int k = 0; k < 256; ++k) {
      float y = thd[t * 256 + k];
      dot += mbs[k] * y;
      yn2 += y * y;
    }
    float den = xn * sqrtf(yn2);
    v = (den > 0.f) ? dot / den : 0.f;
  }
  sim[t] = v;
  __syncthreads();
  for (int it = 0; it < 10; ++it) {
    red[t] = sim[t]; redi[t] = t;
    __syncthreads();
    for (int o = 128; o; o >>= 1) {
      if (t < o) {
        if (red[t + o] > red[t] || (red[t + o] == red[t] && redi[t + o] < redi[t])) {
          red[t] = red[t + o]; redi[t] = redi[t + o];
        }
      }
      __syncthreads();
    }
    if (t == 0) { int bi = redi[0]; dayidx[d * 10 + it] = bi; sim[bi] = -INFINITY; }
    __syncthreads();
  }
}

__global__ void rowsrc_kernel(const int* __restrict__ dayidx, int* __restrict__ rowsrc) {
  int r = blockIdx.x * 256 + threadIdx.x;
  if (r < NSAMP) rowsrc[r] = dayidx[r >> 9] * 512 + (r & 511);
}

__global__ void rownorm_kernel(const float* __restrict__ X, float* __restrict__ out, int rows) {
  int w = threadIdx.x >> 6;
  int lane = threadIdx.x & 63;
  int row = blockIdx.x * 4 + w;
  if (row >= rows) return;
  float4 x = *(const float4*)(X + (size_t)row * 256 + lane * 4);
  float s = x.x * x.x + x.y * x.y + x.z * x.z + x.w * x.w;
#pragma unroll
  for (int o = 32; o; o >>= 1) s += __shfl_down(s, o, 64);
  if (lane == 0) out[row] = sqrtf(s);
}

__global__ void qnorm_kernel(float* __restrict__ q, const float* __restrict__ qn) {
  int i = blockIdx.x * 256 + threadIdx.x;
  int row = i >> 8;
  float n = qn[row];
  q[i] = (n > 0.f) ? q[i] / n : 0.f;
}

__global__ void khT_kernel(const float* __restrict__ kh, const float* __restrict__ khn,
                           float* __restrict__ khT) {
  __shared__ float tile[32][33];
  int jb = blockIdx.x * 32;
  int kb = blockIdx.y * 32;
  int tx = threadIdx.x & 31, tyy = threadIdx.x >> 5;
  for (int rr = tyy; rr < 32; rr += 8) {
    float n = khn[jb + rr];
    float v = kh[(size_t)(jb + rr) * 256 + kb + tx];
    tile[rr][tx] = (n > 0.f) ? v / n : 0.f;
  }
  __syncthreads();
  for (int rr = tyy; rr < 32; rr += 8) {
    khT[(size_t)(kb + rr) * NSAMP + jb + tx] = tile[tx][rr];
  }
}

// ---------------------------------------------------------------- cs GEMM + top-10 (split, XCD-swizzled)
__global__ __launch_bounds__(256, 4)
void csmax_kernel(const float* __restrict__ qh, const float* __restrict__ khT,
                  float* __restrict__ topvp, int* __restrict__ topip)
{
  __shared__ float4 qs[256][2];
  __shared__ float csch[8 * 512];
  const int tid = threadIdx.x;
  const int split = blockIdx.x & 7;
  const int m0 = (blockIdx.x >> 3) * 8;
  {
    int k = tid;
    float4 v0, v1;
    v0.x = qh[(size_t)(m0 + 0) * 256 + k]; v0.y = qh[(size_t)(m0 + 1) * 256 + k];
    v0.z = qh[(size_t)(m0 + 2) * 256 + k]; v0.w = qh[(size_t)(m0 + 3) * 256 + k];
    v1.x = qh[(size_t)(m0 + 4) * 256 + k]; v1.y = qh[(size_t)(m0 + 5) * 256 + k];
    v1.z = qh[(size_t)(m0 + 6) * 256 + k]; v1.w = qh[(size_t)(m0 + 7) * 256 + k];
    qs[k][0] = v0; qs[k][1] = v1;
  }
  __syncthreads();
  const int lane = tid & 63;
  const int wv = tid >> 6;

  float tv0[10], tv1[10];
  int   tj0[10], tj1[10];
  int   tn0 = 0, tn1 = 0;
  float tmv0 = -INFINITY, tmv1 = -INFINITY;
  int   tmi0 = 0, tmi1 = 0;

  auto process_row = [&](int r, float (&tv)[10], int (&tj)[10], int& tn,
                         float& tmv, int& tmi, int jb) {
    float4 c0 = *(const float4*)&csch[r * 512 + lane * 8];
    float4 c1 = *(const float4*)&csch[r * 512 + lane * 8 + 4];
    float cv[8] = {c0.x, c0.y, c0.z, c0.w, c1.x, c1.y, c1.z, c1.w};
    const int cj0 = jb + lane * 8;
    while (true) {
      float bv = -INFINITY; int bj = 0x7fffffff;
#pragma unroll
      for (int u = 0; u < 8; ++u) {
        if (cv[u] > bv) { bv = cv[u]; bj = cj0 + u; }
      }
#pragma unroll
      for (int o = 32; o; o >>= 1) {
        float ov = __shfl_down(bv, o, 64);
        int   oj = __shfl_down(bj, o, 64);
        if (ov > bv || (ov == bv && oj < bj)) { bv = ov; bj = oj; }
      }
      bv = __shfl(bv, 0, 64); bj = __shfl(bj, 0, 64);
      bool take;
      if (tn < 10) take = true;
      else take = (bv > tmv) || (bv == tmv && bj < tmi);
      if (!take) break;
      if (tn < 10) {
#pragma unroll
        for (int s = 0; s < 10; ++s) if (s == tn) { tv[s] = bv; tj[s] = bj; }
        tn++;
        if (tn == 10) {
          float mv = tv[0]; int mi = tj[0];
#pragma unroll
          for (int s = 1; s < 10; ++s) {
            bool w = (tv[s] < mv) || (tv[s] == mv && tj[s] > mi);
            if (w) { mv = tv[s]; mi = tj[s]; }
          }
          tmv = mv; tmi = mi;
        }
      } else {
        int ms = 0; float mv = tv[0]; int mi = tj[0];
#pragma unroll
        for (int s = 1; s < 10; ++s) {
          bool w = (tv[s] < mv) || (tv[s] == mv && tj[s] > mi);
          if (w) { ms = s; mv = tv[s]; mi = tj[s]; }
        }
#pragma unroll
        for (int s = 0; s < 10; ++s) if (s == ms) { tv[s] = bv; tj[s] = bj; }
        mv = tv[0]; mi = tj[0];
#pragma unroll
        for (int s = 1; s < 10; ++s) {
          bool w = (tv[s] < mv) || (tv[s] == mv && tj[s] > mi);
          if (w) { mv = tv[s]; mi = tj[s]; }
        }
        tmv = mv; tmi = mi;
      }
#pragma unroll
      for (int u = 0; u < 8; ++u) if (cj0 + u == bj) cv[u] = -INFINITY;
    }
  };

  for (int ci = 0; ci < 5; ++ci) {
    const int ch = split * 5 + ci;
    const int jb = ch * 512;
    float acc[8][2];
#pragma unroll
    for (int r = 0; r < 8; ++r) { acc[r][0] = 0.f; acc[r][1] = 0.f; }
    const float* kp = khT + jb + tid;

    float b0c[4], b1c[4], b0n[4], b1n[4];
#pragma unroll
    for (int kk = 0; kk < 4; ++kk) {
      b0c[kk] = kp[(size_t)kk * NSAMP];
      b1c[kk] = kp[(size_t)kk * NSAMP + 256];
    }
    for (int k4 = 0; k4 < 64; ++k4) {
      int nk4 = (k4 + 1) & 63;
      const float* pn = kp + (size_t)nk4 * 4 * NSAMP;
#pragma unroll
      for (int kk = 0; kk < 4; ++kk) {
        b0n[kk] = pn[(size_t)kk * NSAMP];
        b1n[kk] = pn[(size_t)kk * NSAMP + 256];
      }
#pragma unroll
      for (int kk = 0; kk < 4; ++kk) {
        float4 qa = qs[k4 * 4 + kk][0];
        float4 qb = qs[k4 * 4 + kk][1];
        float b0 = b0c[kk], b1 = b1c[kk];
        acc[0][0] += qa.x * b0; acc[1][0] += qa.y * b0; acc[2][0] += qa.z * b0; acc[3][0] += qa.w * b0;
        acc[4][0] += qb.x * b0; acc[5][0] += qb.y * b0; acc[6][0] += qb.z * b0; acc[7][0] += qb.w * b0;
        acc[0][1] += qa.x * b1; acc[1][1] += qa.y * b1; acc[2][1] += qa.z * b1; acc[3][1] += qa.w * b1;
        acc[4][1] += qb.x * b1; acc[5][1] += qb.y * b1; acc[6][1] += qb.z * b1; acc[7][1] += qb.w * b1;
      }
#pragma unroll
      for (int q = 0; q < 4; ++q) { b0c[q] = b0n[q]; b1c[q] = b1n[q]; }
    }
    __syncthreads();
#pragma unroll
    for (int r = 0; r < 8; ++r) {
      csch[r * 512 + tid] = acc[r][0];
      csch[r * 512 + 256 + tid] = acc[r][1];
    }
    __syncthreads();
    process_row(wv,     tv0, tj0, tn0, tmv0, tmi0, jb);
    process_row(wv + 4, tv1, tj1, tn1, tmv1, tmi1, jb);
  }
  __syncthreads();

  if (lane == 0) {
    int row0 = m0 + wv;
#pragma unroll
    for (int s = 0; s < 10; ++s) {
      topvp[(size_t)row0 * 80 + split * 10 + s] = tv0[s];
      topip[(size_t)row0 * 80 + split * 10 + s] = tj0[s];
    }
    int row1 = m0 + wv + 4;
#pragma unroll
    for (int s = 0; s < 10; ++s) {
      topvp[(size_t)row1 * 80 + split * 10 + s] = tv1[s];
      topip[(size_t)row1 * 80 + split * 10 + s] = tj1[s];
    }
  }
}

// merge 8 splits x 10 candidates -> global top-10 per row (value desc, idx asc)
__global__ void merge_topk(const float* __restrict__ topvp, const int* __restrict__ topip,
                           float* __restrict__ topv, int* __restrict__ topi)
{
  const int wv = threadIdx.x >> 6;
  const int lane = threadIdx.x & 63;
  const int row = blockIdx.x * 4 + wv;
  float v0 = topvp[(size_t)row * 80 + lane];
  int   i0 = topip[(size_t)row * 80 + lane];
  float v1 = (lane < 16) ? topvp[(size_t)row * 80 + 64 + lane] : -INFINITY;
  int   i1 = (lane < 16) ? topip[(size_t)row * 80 + 64 + lane] : 0x7fffffff;
  for (int s = 0; s < 10; ++s) {
    float bv = v0; int bj = i0;
    if (v1 > bv || (v1 == bv && i1 < bj)) { bv = v1; bj = i1; }
#pragma unroll
    for (int o = 1; o < 64; o <<= 1) {
      float ov = __shfl_xor(bv, o, 64);
      int   oj = __shfl_xor(bj, o, 64);
      if (ov > bv || (ov == bv && oj < bj)) { bv = ov; bj = oj; }
    }
    if (lane == 0) { topv[row * 10 + s] = bv; topi[row * 10 + s] = bj; }
    if (i0 == bj) { v0 = -INFINITY; i0 = 0x7fffffff; }
    if (i1 == bj) { v1 = -INFINITY; i1 = 0x7fffffff; }
  }
}

// ---------------------------------------------------------------- final: agg + fc
__global__ void final_kernel(const float* __restrict__ mb, const float* __restrict__ kh,
                             const float* __restrict__ topv, const int* __restrict__ topi,
                             const float* __restrict__ fcW, const float* __restrict__ fcb,
                             float* __restrict__ y)
{
  __shared__ float red[256];
  int n = blockIdx.x, c = threadIdx.x;
  float agg = 0.f;
#pragma unroll
  for (int k = 0; k < 10; ++k) {
    float w = topv[n * 10 + k] / 10.0f;
    int idx = topi[n * 10 + k];
    agg += w * kh[(size_t)idx * 256 + c];
  }
  float val = fcW[c] * mb[(size_t)n * 256 + c] + fcW[256 + c] * agg;
  red[c] = val;
  __syncthreads();
  for (int o = 128; o; o >>= 1) { if (c < o) red[c] += red[c + o]; __syncthreads(); }
  if (c == 0) y[n] = red[0] + fcb[0];
}

// ---------------------------------------------------------------- launch
extern "C" void kernel_launch(void* const* d_in, const int* in_sizes, int n_in,
                              void* d_out, int out_size, void* d_ws, size_t ws_size,
                              hipStream_t stream)
{
  const float* inp    = (const float*)d_in[0];
  const float* trainh = (const float*)d_in[1];
  const float* thd    = (const float*)d_in[2];
  const float* Wih0   = (const float*)d_in[3];
  const float* Whh0   = (const float*)d_in[4];
  const float* bih0   = (const float*)d_in[5];
  const float* bhh0   = (const float*)d_in[6];
  const float* Wih1   = (const float*)d_in[7];
  const float* Whh1   = (const float*)d_in[8];
  const float* bih1   = (const float*)d_in[9];
  const float* bhh1   = (const float*)d_in[10];
  const float* lin0W  = (const float*)d_in[11];
  const float* lin0b  = (const float*)d_in[12];
  const float* lin1W  = (const float*)d_in[13];
  const float* lin1b  = (const float*)d_in[14];
  const float* lin2W  = (const float*)d_in[15];
  const float* lin2b  = (const float*)d_in[16];
  const float* p1W    = (const float*)d_in[17];
  const float* p2W    = (const float*)d_in[18];
  const float* fcW    = (const float*)d_in[19];
  const float* fcb    = (const float*)d_in[20];

  float* ws = (float*)d_ws;
  float* WT_hh0 = ws + 0;          // 256x768
  float* WTcat  = ws + 196608;     // 512x768
  float* WT_l0  = ws + 589824;     // 256x512
  float* WT_l1  = ws + 720896;     // 512x512
  float* WT_l2  = ws + 983040;     // 512x256
  float* WT_p1  = ws + 1114112;    // 256x256
  float* WT_p2  = ws + 1179648;    // 256x256
  float* hrow   = ws + 1245184;    // 2048x256
  float* mb1    = ws + 3342336;    // 2048x512 (reused for topk candidates)
  float* mb2    = ws + 4390912;    // 2048x512 (WT_ih0 during GRU; mbday partials later)
  float* mbf    = ws + 5439488;    // 2048x256
  float* mbday  = ws + 5963776;    // 4x256
  float* qbuf   = ws + 5964800;    // 2048x256
  float* kh     = ws + 6489088;    // 20480x256
  float* khT    = ws + 11731968;   // 256x20480 (normalized)
  float* khn    = ws + 16974848;   // 20480
  float* qn     = ws + 16995328;   // 2048
  float* topv   = ws + 16997376;   // 2048x10
  int*   dayidx = (int*)(ws + 17017856);
  int*   rowsrc = (int*)(ws + 17017920);
  int*   topi   = (int*)(ws + 17038400);
  float* topvp  = mb1;                       // 2048x80
  int*   topip  = (int*)(mb1 + 163840);      // 2048x80
  float* WT_ih0 = mb2;                       // 6x768 (used only during gru)
  float* mbpart = mb2;                       // 4x8x256 (after GRU)

  PrepArgs pa;
  pa.src[0] = Whh0;  pa.dst[0] = WT_hh0; pa.N[0] = 768; pa.K[0] = 256; pa.ro[0] = 0;
  pa.src[1] = Wih1;  pa.dst[1] = WTcat;  pa.N[1] = 768; pa.K[1] = 256; pa.ro[1] = 0;
  pa.src[2] = Whh1;  pa.dst[2] = WTcat;  pa.N[2] = 768; pa.K[2] = 256; pa.ro[2] = 256;
  pa.src[3] = lin0W; pa.dst[3] = WT_l0;  pa.N[3] = 512; pa.K[3] = 256; pa.ro[3] = 0;
  pa.src[4] = lin1W; pa.dst[4] = WT_l1;  pa.N[4] = 512; pa.K[4] = 512; pa.ro[4] = 0;
  pa.src[5] = lin2W; pa.dst[5] = WT_l2;  pa.N[5] = 256; pa.K[5] = 512; pa.ro[5] = 0;
  pa.src[6] = p1W;   pa.dst[6] = WT_p1;  pa.N[6] = 256; pa.K[6] = 256; pa.ro[6] = 0;
  pa.src[7] = p2W;   pa.dst[7] = WT_p2;  pa.N[7] = 256; pa.K[7] = 256; pa.ro[7] = 0;
  pa.src[8] = Wih0;  pa.dst[8] = WT_ih0; pa.N[8] = 768; pa.K[8] = 6;   pa.ro[8] = 0;
  prep_weights<<<dim3(64, 9), dim3(256), 0, stream>>>(pa);

  gru_pipe<<<256, 1024, 0, stream>>>(inp, WT_hh0, WTcat, WT_ih0, bih0, bhh0, bih1, bhh1, hrow);

  gemm_act<<<dim3(16, 64), dim3(32, 8), 0, stream>>>(hrow, nullptr, WT_l0, lin0b, mb1, 2048, 512, 256, 1);
  gemm_act<<<dim3(16, 64), dim3(32, 8), 0, stream>>>(mb1, nullptr, WT_l1, lin1b, mb2, 2048, 512, 512, 1);
  gemm_act<<<dim3(8, 64),  dim3(32, 8), 0, stream>>>(mb2, nullptr, WT_l2, lin2b, mbf, 2048, 256, 512, 1);

  mbday_part<<<dim3(4, 8), 256, 0, stream>>>(mbf, mbpart);
  mbday_fin<<<4, 256, 0, stream>>>(mbpart, mbday);
  daytopk_kernel<<<4, 256, 0, stream>>>(mbday, thd, dayidx);
  rowsrc_kernel<<<80, 256, 0, stream>>>(dayidx, rowsrc);

  gemm_act<<<dim3(8, 640), dim3(32, 8), 0, stream>>>(trainh, rowsrc, WT_p2, nullptr, kh, 20480, 256, 256, 0);
  gemm_act<<<dim3(8, 64),  dim3(32, 8), 0, stream>>>(mbf, nullptr, WT_p1, nullptr, qbuf, 2048, 256, 256, 0);

  rownorm_kernel<<<5120, 256, 0, stream>>>(kh, khn, 20480);
  rownorm_kernel<<<512, 256, 0, stream>>>(qbuf, qn, 2048);
  qnorm_kernel<<<2048, 256, 0, stream>>>(qbuf, qn);
  khT_kernel<<<dim3(640, 8), 256, 0, stream>>>(kh, khn, khT);

  csmax_kernel<<<2048, 256, 0, stream>>>(qbuf, khT, topvp, topip);
  merge_topk<<<512, 256, 0, stream>>>(topvp, topip, topv, topi);
  final_kernel<<<2048, 256, 0, stream>>>(mbf, kh, topv, topi, fcW, fcb, (float*)d_out);

  (void)in_sizes; (void)n_in; (void)out_size; (void)ws_size;
}

// Round 9
// 3623.984 us; speedup vs baseline: 12.8020x; 1.2837x over previous
//
#include <hip/hip_runtime.h>
#include <cmath>
#include <cstdint>

#define D_FEAT 6
#define T_SEQ  60
#define HID    256
#define G3     768
#define NROW   2048
#define NSAMP  20480

__device__ __forceinline__ float sigmoidf_(float x) { return 1.0f / (1.0f + expf(-x)); }

// ---------------------------------------------------------------- weight prep
struct PrepArgs {
  const float* src[9];
  float* dst[9];
  int N[9], K[9], ro[9];
};

__global__ void prep_weights(PrepArgs a) {
  int seg = blockIdx.y;
  const float* S = a.src[seg];
  float* D = a.dst[seg];
  int N = a.N[seg], K = a.K[seg], ro = a.ro[seg];
  int total = N * K;
  for (int i = blockIdx.x * blockDim.x + threadIdx.x; i < total; i += gridDim.x * blockDim.x) {
    int n = i / K, k = i - n * K;
    D[(size_t)(k + ro) * N + n] = S[i];   // WT[k][n] = W[n][k]
  }
}

// ---------------------------------------------------------------- persistent pipelined GRU v5
// Grid 256 x 512 threads (2 waves/SIMD, 128-VGPR budget — 1024-thr blocks get
// only 64 VGPRs and spill [R8 post-mortem]). Block owns 8 stocks.
// Thread (col = tid&255, khalf = tid>>8) owns outputs {col,256+col,512+col},
// all 8 rows, khalf's half of K. PIPELINED phases: phase p = layer0(t=p) +
// layer1(t=p-1) -> 122 barriers vs 240. Asymmetric schedule so each half keeps
// only its LAST kloop's accumulators in registers (~92 live):
//   khalf0: l1-kloops -> dump excA -> gh-kloop (keep) -> xw -> combine layer0
//   khalf1: gh-kloop -> dump excB -> l1-kloops (keep)       -> combine layer1
// Partial-add order (khalf0 + khalf1) identical to R6/R8 -> absmax 0.0.
__device__ __forceinline__ void kloop128(const float* __restrict__ A,   // LDS [k*8+row] (half-base)
                                         const float* __restrict__ B,   // global + col (half-base)
                                         float (&acc)[3][8])
{
  float4 Aa[4][2];
  float  Bb[2][12];
#pragma unroll
  for (int c = 0; c < 4; ++c) {
    Aa[c][0] = *(const float4*)(A + c * 8);
    Aa[c][1] = *(const float4*)(A + c * 8 + 4);
  }
#pragma unroll
  for (int c = 0; c < 4; ++c)
#pragma unroll
    for (int u = 0; u < 3; ++u)
      Bb[0][c * 3 + u] = B[(size_t)c * G3 + u * 256];

  for (int kb = 0; kb < 128; kb += 8) {
    {
      const float* p = B + (size_t)(kb + 4) * G3;
#pragma unroll
      for (int c = 0; c < 4; ++c)
#pragma unroll
        for (int u = 0; u < 3; ++u)
          Bb[1][c * 3 + u] = p[(size_t)c * G3 + u * 256];
    }
#pragma unroll
    for (int c = 0; c < 4; ++c) {
      float4 alo = Aa[c][0], ahi = Aa[c][1];
      int kn = kb + 4 + c;                 // max 127
      Aa[c][0] = *(const float4*)(A + kn * 8);
      Aa[c][1] = *(const float4*)(A + kn * 8 + 4);
#pragma unroll
      for (int u = 0; u < 3; ++u) {
        float b = Bb[0][c * 3 + u];
        acc[u][0] += alo.x * b; acc[u][1] += alo.y * b;
        acc[u][2] += alo.z * b; acc[u][3] += alo.w * b;
        acc[u][4] += ahi.x * b; acc[u][5] += ahi.y * b;
        acc[u][6] += ahi.z * b; acc[u][7] += ahi.w * b;
      }
    }
    {
      int kw = (kb + 8) & 127;
      const float* p = B + (size_t)kw * G3;
#pragma unroll
      for (int c = 0; c < 4; ++c)
#pragma unroll
        for (int u = 0; u < 3; ++u)
          Bb[0][c * 3 + u] = p[(size_t)c * G3 + u * 256];
    }
#pragma unroll
    for (int c = 0; c < 4; ++c) {
      float4 alo = Aa[c][0], ahi = Aa[c][1];
      int kn = (kb + 8 + c) & 127;
      Aa[c][0] = *(const float4*)(A + kn * 8);
      Aa[c][1] = *(const float4*)(A + kn * 8 + 4);
#pragma unroll
      for (int u = 0; u < 3; ++u) {
        float b = Bb[1][c * 3 + u];
        acc[u][0] += alo.x * b; acc[u][1] += alo.y * b;
        acc[u][2] += alo.z * b; acc[u][3] += alo.w * b;
        acc[u][4] += ahi.x * b; acc[u][5] += ahi.y * b;
        acc[u][6] += ahi.z * b; acc[u][7] += ahi.w * b;
      }
    }
  }
}

__global__ __launch_bounds__(512, 1)
void gru_pipe(const float* __restrict__ inp, const float* __restrict__ WThh0,
              const float* __restrict__ WTcat, const float* __restrict__ WTih0,
              const float* __restrict__ bih0, const float* __restrict__ bhh0,
              const float* __restrict__ bih1, const float* __restrict__ bhh1,
              float* __restrict__ hrow)
{
  __shared__ float h0A[2048], h0B[2048];   // [k*8+row] ping-pong
  __shared__ float h1A[2048], h1B[2048];
  __shared__ float xls[2880];              // [(i*60+t)*8 + row]
  __shared__ float excA[256 * 33];         // khalf0 layer1 partials (32 used)
  __shared__ float excB[256 * 25];         // khalf1 layer0 partials (24 used)

  const int tid = threadIdx.x;
  const int col = tid & 255;
  const int khalf = tid >> 8;
  const int m0 = blockIdx.x * 8;
  const int aoff = khalf * 1024;           // khalf*128 k-rows * 8

  for (int c = tid; c < 2880; c += 512) {
    int row = c / 360, it = c - row * 360;
    xls[it * 8 + row] = inp[(size_t)(m0 + row) * 360 + it];
  }
  // h0A = h0(-1) = 0 (phase 0 cur); h1B = h1(-1) = 0 (phase 1 cur)
  for (int c = tid; c < 2048; c += 512) { h0A[c] = 0.f; h1B[c] = 0.f; }

  float h0c[8] = {0,0,0,0,0,0,0,0};        // lives on khalf 0
  float h1c[8] = {0,0,0,0,0,0,0,0};        // lives on khalf 1

  float b_ih0[3], b_hh0[3], b_ih1[3], b_hh1[3];
#pragma unroll
  for (int u = 0; u < 3; ++u) {
    int o = u * 256 + col;
    b_ih0[u] = bih0[o]; b_hh0[u] = bhh0[o];
    b_ih1[u] = bih1[o]; b_hh1[u] = bhh1[o];
  }
  __syncthreads();

  const float* Bhh0 = WThh0 + (size_t)(khalf * 128) * G3 + col;
  const float* Bc0  = WTcat + (size_t)(khalf * 128) * G3 + col;
  const float* Bc1  = WTcat + (size_t)(256 + khalf * 128) * G3 + col;
  float* eA = excA + col * 33;
  float* eB = excB + col * 25;

  for (int p = 0; p <= 60; ++p) {
    const float* h0cur = (p & 1) ? h0B : h0A;
    float*       h0nxt = (p & 1) ? h0A : h0B;
    const float* h1cur = (p & 1) ? h1B : h1A;
    float*       h1nxt = (p & 1) ? h1A : h1B;

    float gh[3][8];                        // layer0 partials (kept on khalf0)
    float l1[3][8], xn8[8];                // layer1 partials (kept on khalf1)
    float xw[3][8];                        // layer0 x-part (khalf0)

    if (khalf == 1) {
      // ---- gh first, dump; then l1, keep ----
      if (p < 60) {
#pragma unroll
        for (int u = 0; u < 3; ++u)
#pragma unroll
          for (int r = 0; r < 8; ++r) gh[u][r] = 0.f;
        kloop128(h0cur + aoff, Bhh0, gh);
#pragma unroll
        for (int u = 0; u < 3; ++u)
#pragma unroll
          for (int r = 0; r < 8; ++r) eB[u * 8 + r] = gh[u][r];
      }
      if (p > 0) {
#pragma unroll
        for (int u = 0; u < 3; ++u)
#pragma unroll
          for (int r = 0; r < 8; ++r) l1[u][r] = 0.f;
        kloop128(h0cur + aoff, Bc0, l1);
#pragma unroll
        for (int r = 0; r < 8; ++r) { xn8[r] = l1[2][r]; l1[2][r] = 0.f; }
        kloop128(h1cur + aoff, Bc1, l1);
      }
    } else {
      // ---- l1 first, dump; then gh keep; then xw ----
      if (p > 0) {
#pragma unroll
        for (int u = 0; u < 3; ++u)
#pragma unroll
          for (int r = 0; r < 8; ++r) l1[u][r] = 0.f;
        kloop128(h0cur + aoff, Bc0, l1);
#pragma unroll
        for (int r = 0; r < 8; ++r) { xn8[r] = l1[2][r]; l1[2][r] = 0.f; }
        kloop128(h1cur + aoff, Bc1, l1);
#pragma unroll
        for (int r = 0; r < 8; ++r) {
          eA[r]      = l1[0][r];
          eA[8 + r]  = l1[1][r];
          eA[16 + r] = xn8[r];
          eA[24 + r] = l1[2][r];
        }
      }
      if (p < 60) {
#pragma unroll
        for (int u = 0; u < 3; ++u)
#pragma unroll
          for (int r = 0; r < 8; ++r) gh[u][r] = 0.f;
        kloop128(h0cur + aoff, Bhh0, gh);
        // layer0 x-part (K=6)
#pragma unroll
        for (int u = 0; u < 3; ++u)
#pragma unroll
          for (int r = 0; r < 8; ++r) xw[u][r] = b_ih0[u];
#pragma unroll
        for (int i = 0; i < 6; ++i) {
          float4 xlo = *(const float4*)&xls[(i * 60 + p) * 8];
          float4 xhi = *(const float4*)&xls[(i * 60 + p) * 8 + 4];
#pragma unroll
          for (int u = 0; u < 3; ++u) {
            float b = WTih0[i * G3 + u * 256 + col];
            xw[u][0] += xlo.x * b; xw[u][1] += xlo.y * b;
            xw[u][2] += xlo.z * b; xw[u][3] += xlo.w * b;
            xw[u][4] += xhi.x * b; xw[u][5] += xhi.y * b;
            xw[u][6] += xhi.z * b; xw[u][7] += xhi.w * b;
          }
        }
      }
    }
    __syncthreads();

    if (khalf == 0) {
      if (p < 60) {
        float hn[8];
#pragma unroll
        for (int r = 0; r < 8; ++r) {
          float g0 = gh[0][r] + eB[r];           // khalf0 + khalf1 (R6 order)
          float g1 = gh[1][r] + eB[8 + r];
          float g2 = gh[2][r] + eB[16 + r];
          float rr = sigmoidf_(xw[0][r] + (g0 + b_hh0[0]));
          float zz = sigmoidf_(xw[1][r] + (g1 + b_hh0[1]));
          float nn = tanhf(xw[2][r] + rr * (g2 + b_hh0[2]));
          h0c[r] = (1.f - zz) * nn + zz * h0c[r];
          hn[r] = h0c[r];
        }
        *(float4*)&h0nxt[col * 8]     = *(float4*)&hn[0];
        *(float4*)&h0nxt[col * 8 + 4] = *(float4*)&hn[4];
      }
    } else {
      if (p > 0) {
        float hn[8];
#pragma unroll
        for (int r = 0; r < 8; ++r) {
          float ra = eA[r]      + l1[0][r];      // khalf0 + khalf1 (R6 order)
          float za = eA[8 + r]  + l1[1][r];
          float xa = eA[16 + r] + xn8[r];
          float ha = eA[24 + r] + l1[2][r];
          float rr = sigmoidf_((ra + b_ih1[0]) + b_hh1[0]);
          float zz = sigmoidf_((za + b_ih1[1]) + b_hh1[1]);
          float nn = tanhf((xa + b_ih1[2]) + rr * (ha + b_hh1[2]));
          h1c[r] = (1.f - zz) * nn + zz * h1c[r];
          hn[r] = h1c[r];
        }
        *(float4*)&h1nxt[col * 8]     = *(float4*)&hn[0];
        *(float4*)&h1nxt[col * 8 + 4] = *(float4*)&hn[4];
      }
    }
    __syncthreads();
  }

  if (khalf == 1) {
#pragma unroll
    for (int r = 0; r < 8; ++r)
      hrow[(size_t)(m0 + r) * 256 + col] = h1c[r];
  }
}

// ---------------------------------------------------------------- generic GEMM
__global__ __launch_bounds__(256, 2)
void gemm_act(const float* __restrict__ A, const int* __restrict__ rowsrc,
              const float* __restrict__ WT, const float* __restrict__ bias,
              float* __restrict__ C, int M, int N, int K, int act)
{
  __shared__ float4 As4[128 * 32];
  const int tx = threadIdx.x, ty = threadIdx.y;
  const int tid = ty * 32 + tx;
  const int n0 = blockIdx.x * 32, m0 = blockIdx.y * 32;
  const int K4 = K >> 2;

  for (int c = tid; c < K4 * 32; c += 256) {
    int k4 = c % K4, m = c / K4;
    int row = m0 + m;
    if (rowsrc) row = rowsrc[row];
    As4[k4 * 32 + m] = *(const float4*)(A + (size_t)row * K + k4 * 4);
  }
  __syncthreads();

  float acc[4] = {0,0,0,0};
  const int n = n0 + tx;
  const float* pb = WT + n;

  float bc[4], bn_[4];
#pragma unroll
  for (int kk = 0; kk < 4; ++kk) bc[kk] = pb[(size_t)kk * N];
  for (int k4 = 0; k4 < K4; ++k4) {
    int nk4 = (k4 + 1 < K4) ? (k4 + 1) : 0;
    const float* pn = pb + (size_t)nk4 * 4 * N;
#pragma unroll
    for (int kk = 0; kk < 4; ++kk) bn_[kk] = pn[(size_t)kk * N];
    float4 a0 = As4[k4 * 32 + ty * 4 + 0];
    float4 a1 = As4[k4 * 32 + ty * 4 + 1];
    float4 a2 = As4[k4 * 32 + ty * 4 + 2];
    float4 a3 = As4[k4 * 32 + ty * 4 + 3];
#pragma unroll
    for (int kk = 0; kk < 4; ++kk) {
      float b = bc[kk];
      acc[0] += ((const float*)&a0)[kk] * b;
      acc[1] += ((const float*)&a1)[kk] * b;
      acc[2] += ((const float*)&a2)[kk] * b;
      acc[3] += ((const float*)&a3)[kk] * b;
    }
#pragma unroll
    for (int q = 0; q < 4; ++q) bc[q] = bn_[q];
  }
  float bb = bias ? bias[n] : 0.f;
#pragma unroll
  for (int r = 0; r < 4; ++r) {
    float v = acc[r] + bb;
    if (act) v = (v >= 0.f) ? v : 0.01f * v;
    C[(size_t)(m0 + ty * 4 + r) * N + n] = v;
  }
}

// ---------------------------------------------------------------- small stages
__global__ void mbday_part(const float* __restrict__ mbf, float* __restrict__ part) {
  int d = blockIdx.x, sl = blockIdx.y, c = threadIdx.x;
  float s = 0.f;
  int base = d * 512 + sl * 64;
  for (int st = 0; st < 64; ++st) s += mbf[(size_t)(base + st) * 256 + c];
  part[(size_t)(d * 8 + sl) * 256 + c] = s;
}

__global__ void mbday_fin(const float* __restrict__ part, float* __restrict__ mbday) {
  int d = blockIdx.x, c = threadIdx.x;
  float s = 0.f;
#pragma unroll
  for (int p = 0; p < 8; ++p) s += part[(size_t)(d * 8 + p) * 256 + c];
  mbday[d * 256 + c] = s * (1.0f / 512.0f);
}

__global__ void daytopk_kernel(const float* __restrict__ mbday, const float* __restrict__ thd,
                               int* __restrict__ dayidx) {
  __shared__ float mbs[256];
  __shared__ float sim[256];
  __shared__ float red[256];
  __shared__ int   redi[256];
  const int d = blockIdx.x, t = threadIdx.x;
  mbs[t] = mbday[d * 256 + t];
  __syncthreads();
  red[t] = mbs[t] * mbs[t];
  __syncthreads();
  for (int o = 128; o; o >>= 1) { if (t < o) red[t] += red[t + o]; __syncthreads(); }
  float xn = sqrtf(red[0]);
  float v = -INFINITY;
  if (t < 240) {
    float dot = 0.f, yn2 = 0.f;
    for (int k = 0; k < 256; ++k) {
      float y = thd[t * 256 + k];
      dot += mbs[k] * y;
      yn2 += y * y;
    }
    float den = xn * sqrtf(yn2);
    v = (den > 0.f) ? dot / den : 0.f;
  }
  sim[t] = v;
  __syncthreads();
  for (int it = 0; it < 10; ++it) {
    red[t] = sim[t]; redi[t] = t;
    __syncthreads();
    for (int o = 128; o; o >>= 1) {
      if (t < o) {
        if (red[t + o] > red[t] || (red[t + o] == red[t] && redi[t + o] < redi[t])) {
          red[t] = red[t + o]; redi[t] = redi[t + o];
        }
      }
      __syncthreads();
    }
    if (t == 0) { int bi = redi[0]; dayidx[d * 10 + it] = bi; sim[bi] = -INFINITY; }
    __syncthreads();
  }
}

__global__ void rowsrc_kernel(const int* __restrict__ dayidx, int* __restrict__ rowsrc) {
  int r = blockIdx.x * 256 + threadIdx.x;
  if (r < NSAMP) rowsrc[r] = dayidx[r >> 9] * 512 + (r & 511);
}

__global__ void rownorm_kernel(const float* __restrict__ X, float* __restrict__ out, int rows) {
  int w = threadIdx.x >> 6;
  int lane = threadIdx.x & 63;
  int row = blockIdx.x * 4 + w;
  if (row >= rows) return;
  float4 x = *(const float4*)(X + (size_t)row * 256 + lane * 4);
  float s = x.x * x.x + x.y * x.y + x.z * x.z + x.w * x.w;
#pragma unroll
  for (int o = 32; o; o >>= 1) s += __shfl_down(s, o, 64);
  if (lane == 0) out[row] = sqrtf(s);
}

__global__ void qnorm_kernel(float* __restrict__ q, const float* __restrict__ qn) {
  int i = blockIdx.x * 256 + threadIdx.x;
  int row = i >> 8;
  float n = qn[row];
  q[i] = (n > 0.f) ? q[i] / n : 0.f;
}

__global__ void khT_kernel(const float* __restrict__ kh, const float* __restrict__ khn,
                           float* __restrict__ khT) {
  __shared__ float tile[32][33];
  int jb = blockIdx.x * 32;
  int kb = blockIdx.y * 32;
  int tx = threadIdx.x & 31, tyy = threadIdx.x >> 5;
  for (int rr = tyy; rr < 32; rr += 8) {
    float n = khn[jb + rr];
    float v = kh[(size_t)(jb + rr) * 256 + kb + tx];
    tile[rr][tx] = (n > 0.f) ? v / n : 0.f;
  }
  __syncthreads();
  for (int rr = tyy; rr < 32; rr += 8) {
    khT[(size_t)(kb + rr) * NSAMP + jb + tx] = tile[tx][rr];
  }
}

// ---------------------------------------------------------------- cs GEMM + top-10 (split, XCD-swizzled)
__global__ __launch_bounds__(256, 4)
void csmax_kernel(const float* __restrict__ qh, const float* __restrict__ khT,
                  float* __restrict__ topvp, int* __restrict__ topip)
{
  __shared__ float4 qs[256][2];
  __shared__ float csch[8 * 512];
  const int tid = threadIdx.x;
  const int split = blockIdx.x & 7;
  const int m0 = (blockIdx.x >> 3) * 8;
  {
    int k = tid;
    float4 v0, v1;
    v0.x = qh[(size_t)(m0 + 0) * 256 + k]; v0.y = qh[(size_t)(m0 + 1) * 256 + k];
    v0.z = qh[(size_t)(m0 + 2) * 256 + k]; v0.w = qh[(size_t)(m0 + 3) * 256 + k];
    v1.x = qh[(size_t)(m0 + 4) * 256 + k]; v1.y = qh[(size_t)(m0 + 5) * 256 + k];
    v1.z = qh[(size_t)(m0 + 6) * 256 + k]; v1.w = qh[(size_t)(m0 + 7) * 256 + k];
    qs[k][0] = v0; qs[k][1] = v1;
  }
  __syncthreads();
  const int lane = tid & 63;
  const int wv = tid >> 6;

  float tv0[10], tv1[10];
  int   tj0[10], tj1[10];
  int   tn0 = 0, tn1 = 0;
  float tmv0 = -INFINITY, tmv1 = -INFINITY;
  int   tmi0 = 0, tmi1 = 0;

  auto process_row = [&](int r, float (&tv)[10], int (&tj)[10], int& tn,
                         float& tmv, int& tmi, int jb) {
    float4 c0 = *(const float4*)&csch[r * 512 + lane * 8];
    float4 c1 = *(const float4*)&csch[r * 512 + lane * 8 + 4];
    float cv[8] = {c0.x, c0.y, c0.z, c0.w, c1.x, c1.y, c1.z, c1.w};
    const int cj0 = jb + lane * 8;
    while (true) {
      float bv = -INFINITY; int bj = 0x7fffffff;
#pragma unroll
      for (int u = 0; u < 8; ++u) {
        if (cv[u] > bv) { bv = cv[u]; bj = cj0 + u; }
      }
#pragma unroll
      for (int o = 32; o; o >>= 1) {
        float ov = __shfl_down(bv, o, 64);
        int   oj = __shfl_down(bj, o, 64);
        if (ov > bv || (ov == bv && oj < bj)) { bv = ov; bj = oj; }
      }
      bv = __shfl(bv, 0, 64); bj = __shfl(bj, 0, 64);
      bool take;
      if (tn < 10) take = true;
      else take = (bv > tmv) || (bv == tmv && bj < tmi);
      if (!take) break;
      if (tn < 10) {
#pragma unroll
        for (int s = 0; s < 10; ++s) if (s == tn) { tv[s] = bv; tj[s] = bj; }
        tn++;
        if (tn == 10) {
          float mv = tv[0]; int mi = tj[0];
#pragma unroll
          for (int s = 1; s < 10; ++s) {
            bool w = (tv[s] < mv) || (tv[s] == mv && tj[s] > mi);
            if (w) { mv = tv[s]; mi = tj[s]; }
          }
          tmv = mv; tmi = mi;
        }
      } else {
        int ms = 0; float mv = tv[0]; int mi = tj[0];
#pragma unroll
        for (int s = 1; s < 10; ++s) {
          bool w = (tv[s] < mv) || (tv[s] == mv && tj[s] > mi);
          if (w) { ms = s; mv = tv[s]; mi = tj[s]; }
        }
#pragma unroll
        for (int s = 0; s < 10; ++s) if (s == ms) { tv[s] = bv; tj[s] = bj; }
        mv = tv[0]; mi = tj[0];
#pragma unroll
        for (int s = 1; s < 10; ++s) {
          bool w = (tv[s] < mv) || (tv[s] == mv && tj[s] > mi);
          if (w) { mv = tv[s]; mi = tj[s]; }
        }
        tmv = mv; tmi = mi;
      }
#pragma unroll
      for (int u = 0; u < 8; ++u) if (cj0 + u == bj) cv[u] = -INFINITY;
    }
  };

  for (int ci = 0; ci < 5; ++ci) {
    const int ch = split * 5 + ci;
    const int jb = ch * 512;
    float acc[8][2];
#pragma unroll
    for (int r = 0; r < 8; ++r) { acc[r][0] = 0.f; acc[r][1] = 0.f; }
    const float* kp = khT + jb + tid;

    float b0c[4], b1c[4], b0n[4], b1n[4];
#pragma unroll
    for (int kk = 0; kk < 4; ++kk) {
      b0c[kk] = kp[(size_t)kk * NSAMP];
      b1c[kk] = kp[(size_t)kk * NSAMP + 256];
    }
    for (int k4 = 0; k4 < 64; ++k4) {
      int nk4 = (k4 + 1) & 63;
      const float* pn = kp + (size_t)nk4 * 4 * NSAMP;
#pragma unroll
      for (int kk = 0; kk < 4; ++kk) {
        b0n[kk] = pn[(size_t)kk * NSAMP];
        b1n[kk] = pn[(size_t)kk * NSAMP + 256];
      }
#pragma unroll
      for (int kk = 0; kk < 4; ++kk) {
        float4 qa = qs[k4 * 4 + kk][0];
        float4 qb = qs[k4 * 4 + kk][1];
        float b0 = b0c[kk], b1 = b1c[kk];
        acc[0][0] += qa.x * b0; acc[1][0] += qa.y * b0; acc[2][0] += qa.z * b0; acc[3][0] += qa.w * b0;
        acc[4][0] += qb.x * b0; acc[5][0] += qb.y * b0; acc[6][0] += qb.z * b0; acc[7][0] += qb.w * b0;
        acc[0][1] += qa.x * b1; acc[1][1] += qa.y * b1; acc[2][1] += qa.z * b1; acc[3][1] += qa.w * b1;
        acc[4][1] += qb.x * b1; acc[5][1] += qb.y * b1; acc[6][1] += qb.z * b1; acc[7][1] += qb.w * b1;
      }
#pragma unroll
      for (int q = 0; q < 4; ++q) { b0c[q] = b0n[q]; b1c[q] = b1n[q]; }
    }
    __syncthreads();
#pragma unroll
    for (int r = 0; r < 8; ++r) {
      csch[r * 512 + tid] = acc[r][0];
      csch[r * 512 + 256 + tid] = acc[r][1];
    }
    __syncthreads();
    process_row(wv,     tv0, tj0, tn0, tmv0, tmi0, jb);
    process_row(wv + 4, tv1, tj1, tn1, tmv1, tmi1, jb);
  }
  __syncthreads();

  if (lane == 0) {
    int row0 = m0 + wv;
#pragma unroll
    for (int s = 0; s < 10; ++s) {
      topvp[(size_t)row0 * 80 + split * 10 + s] = tv0[s];
      topip[(size_t)row0 * 80 + split * 10 + s] = tj0[s];
    }
    int row1 = m0 + wv + 4;
#pragma unroll
    for (int s = 0; s < 10; ++s) {
      topvp[(size_t)row1 * 80 + split * 10 + s] = tv1[s];
      topip[(size_t)row1 * 80 + split * 10 + s] = tj1[s];
    }
  }
}

// merge 8 splits x 10 candidates -> global top-10 per row (value desc, idx asc)
__global__ void merge_topk(const float* __restrict__ topvp, const int* __restrict__ topip,
                           float* __restrict__ topv, int* __restrict__ topi)
{
  const int wv = threadIdx.x >> 6;
  const int lane = threadIdx.x & 63;
  const int row = blockIdx.x * 4 + wv;
  float v0 = topvp[(size_t)row * 80 + lane];
  int   i0 = topip[(size_t)row * 80 + lane];
  float v1 = (lane < 16) ? topvp[(size_t)row * 80 + 64 + lane] : -INFINITY;
  int   i1 = (lane < 16) ? topip[(size_t)row * 80 + 64 + lane] : 0x7fffffff;
  for (int s = 0; s < 10; ++s) {
    float bv = v0; int bj = i0;
    if (v1 > bv || (v1 == bv && i1 < bj)) { bv = v1; bj = i1; }
#pragma unroll
    for (int o = 1; o < 64; o <<= 1) {
      float ov = __shfl_xor(bv, o, 64);
      int   oj = __shfl_xor(bj, o, 64);
      if (ov > bv || (ov == bv && oj < bj)) { bv = ov; bj = oj; }
    }
    if (lane == 0) { topv[row * 10 + s] = bv; topi[row * 10 + s] = bj; }
    if (i0 == bj) { v0 = -INFINITY; i0 = 0x7fffffff; }
    if (i1 == bj) { v1 = -INFINITY; i1 = 0x7fffffff; }
  }
}

// ---------------------------------------------------------------- final: agg + fc
__global__ void final_kernel(const float* __restrict__ mb, const float* __restrict__ kh,
                             const float* __restrict__ topv, const int* __restrict__ topi,
                             const float* __restrict__ fcW, const float* __restrict__ fcb,
                             float* __restrict__ y)
{
  __shared__ float red[256];
  int n = blockIdx.x, c = threadIdx.x;
  float agg = 0.f;
#pragma unroll
  for (int k = 0; k < 10; ++k) {
    float w = topv[n * 10 + k] / 10.0f;
    int idx = topi[n * 10 + k];
    agg += w * kh[(size_t)idx * 256 + c];
  }
  float val = fcW[c] * mb[(size_t)n * 256 + c] + fcW[256 + c] * agg;
  red[c] = val;
  __syncthreads();
  for (int o = 128; o; o >>= 1) { if (c < o) red[c] += red[c + o]; __syncthreads(); }
  if (c == 0) y[n] = red[0] + fcb[0];
}

// ---------------------------------------------------------------- launch
extern "C" void kernel_launch(void* const* d_in, const int* in_sizes, int n_in,
                              void* d_out, int out_size, void* d_ws, size_t ws_size,
                              hipStream_t stream)
{
  const float* inp    = (const float*)d_in[0];
  const float* trainh = (const float*)d_in[1];
  const float* thd    = (const float*)d_in[2];
  const float* Wih0   = (const float*)d_in[3];
  const float* Whh0   = (const float*)d_in[4];
  const float* bih0   = (const float*)d_in[5];
  const float* bhh0   = (const float*)d_in[6];
  const float* Wih1   = (const float*)d_in[7];
  const float* Whh1   = (const float*)d_in[8];
  const float* bih1   = (const float*)d_in[9];
  const float* bhh1   = (const float*)d_in[10];
  const float* lin0W  = (const float*)d_in[11];
  const float* lin0b  = (const float*)d_in[12];
  const float* lin1W  = (const float*)d_in[13];
  const float* lin1b  = (const float*)d_in[14];
  const float* lin2W  = (const float*)d_in[15];
  const float* lin2b  = (const float*)d_in[16];
  const float* p1W    = (const float*)d_in[17];
  const float* p2W    = (const float*)d_in[18];
  const float* fcW    = (const float*)d_in[19];
  const float* fcb    = (const float*)d_in[20];

  float* ws = (float*)d_ws;
  float* WT_hh0 = ws + 0;          // 256x768
  float* WTcat  = ws + 196608;     // 512x768
  float* WT_l0  = ws + 589824;     // 256x512
  float* WT_l1  = ws + 720896;     // 512x512
  float* WT_l2  = ws + 983040;     // 512x256
  float* WT_p1  = ws + 1114112;    // 256x256
  float* WT_p2  = ws + 1179648;    // 256x256
  float* hrow   = ws + 1245184;    // 2048x256
  float* mb1    = ws + 3342336;    // 2048x512 (reused for topk candidates)
  float* mb2    = ws + 4390912;    // 2048x512 (WT_ih0 during GRU; mbday partials later)
  float* mbf    = ws + 5439488;    // 2048x256
  float* mbday  = ws + 5963776;    // 4x256
  float* qbuf   = ws + 5964800;    // 2048x256
  float* kh     = ws + 6489088;    // 20480x256
  float* khT    = ws + 11731968;   // 256x20480 (normalized)
  float* khn    = ws + 16974848;   // 20480
  float* qn     = ws + 16995328;   // 2048
  float* topv   = ws + 16997376;   // 2048x10
  int*   dayidx = (int*)(ws + 17017856);
  int*   rowsrc = (int*)(ws + 17017920);
  int*   topi   = (int*)(ws + 17038400);
  float* topvp  = mb1;                       // 2048x80
  int*   topip  = (int*)(mb1 + 163840);      // 2048x80
  float* WT_ih0 = mb2;                       // 6x768 (used only during gru)
  float* mbpart = mb2;                       // 4x8x256 (after GRU)

  PrepArgs pa;
  pa.src[0] = Whh0;  pa.dst[0] = WT_hh0; pa.N[0] = 768; pa.K[0] = 256; pa.ro[0] = 0;
  pa.src[1] = Wih1;  pa.dst[1] = WTcat;  pa.N[1] = 768; pa.K[1] = 256; pa.ro[1] = 0;
  pa.src[2] = Whh1;  pa.dst[2] = WTcat;  pa.N[2] = 768; pa.K[2] = 256; pa.ro[2] = 256;
  pa.src[3] = lin0W; pa.dst[3] = WT_l0;  pa.N[3] = 512; pa.K[3] = 256; pa.ro[3] = 0;
  pa.src[4] = lin1W; pa.dst[4] = WT_l1;  pa.N[4] = 512; pa.K[4] = 512; pa.ro[4] = 0;
  pa.src[5] = lin2W; pa.dst[5] = WT_l2;  pa.N[5] = 256; pa.K[5] = 512; pa.ro[5] = 0;
  pa.src[6] = p1W;   pa.dst[6] = WT_p1;  pa.N[6] = 256; pa.K[6] = 256; pa.ro[6] = 0;
  pa.src[7] = p2W;   pa.dst[7] = WT_p2;  pa.N[7] = 256; pa.K[7] = 256; pa.ro[7] = 0;
  pa.src[8] = Wih0;  pa.dst[8] = WT_ih0; pa.N[8] = 768; pa.K[8] = 6;   pa.ro[8] = 0;
  prep_weights<<<dim3(64, 9), dim3(256), 0, stream>>>(pa);

  gru_pipe<<<256, 512, 0, stream>>>(inp, WT_hh0, WTcat, WT_ih0, bih0, bhh0, bih1, bhh1, hrow);

  gemm_act<<<dim3(16, 64), dim3(32, 8), 0, stream>>>(hrow, nullptr, WT_l0, lin0b, mb1, 2048, 512, 256, 1);
  gemm_act<<<dim3(16, 64), dim3(32, 8), 0, stream>>>(mb1, nullptr, WT_l1, lin1b, mb2, 2048, 512, 512, 1);
  gemm_act<<<dim3(8, 64),  dim3(32, 8), 0, stream>>>(mb2, nullptr, WT_l2, lin2b, mbf, 2048, 256, 512, 1);

  mbday_part<<<dim3(4, 8), 256, 0, stream>>>(mbf, mbpart);
  mbday_fin<<<4, 256, 0, stream>>>(mbpart, mbday);
  daytopk_kernel<<<4, 256, 0, stream>>>(mbday, thd, dayidx);
  rowsrc_kernel<<<80, 256, 0, stream>>>(dayidx, rowsrc);

  gemm_act<<<dim3(8, 640), dim3(32, 8), 0, stream>>>(trainh, rowsrc, WT_p2, nullptr, kh, 20480, 256, 256, 0);
  gemm_act<<<dim3(8, 64),  dim3(32, 8), 0, stream>>>(mbf, nullptr, WT_p1, nullptr, qbuf, 2048, 256, 256, 0);

  rownorm_kernel<<<5120, 256, 0, stream>>>(kh, khn, 20480);
  rownorm_kernel<<<512, 256, 0, stream>>>(qbuf, qn, 2048);
  qnorm_kernel<<<2048, 256, 0, stream>>>(qbuf, qn);
  khT_kernel<<<dim3(640, 8), 256, 0, stream>>>(kh, khn, khT);

  csmax_kernel<<<2048, 256, 0, stream>>>(qbuf, khT, topvp, topip);
  merge_topk<<<512, 256, 0, stream>>>(topvp, topip, topv, topi);
  final_kernel<<<2048, 256, 0, stream>>>(mbf, kh, topv, topi, fcW, fcb, (float*)d_out);

  (void)in_sizes; (void)n_in; (void)out_size; (void)ws_size;
}